// Round 14
// baseline (294.944 us; speedup 1.0000x reference)
//
#include <hip/hip_runtime.h>
#include <hip/hip_bf16.h>

#define DEVI static __device__ __forceinline__

typedef __attribute__((ext_vector_type(8))) short short8;
typedef __attribute__((ext_vector_type(4))) float f32x4;

#define B_   8
#define O_   100
#define N_   4096
#define TOKD 2048
#define D_   256
#define K_   128
#define H_   8
#define M_   (B_*N_)   // 32768

DEVI unsigned short f2bf(float f) {
    unsigned u = __float_as_uint(f);
    u = (u + 0x7FFFu + ((u >> 16) & 1u)) >> 16;   // RNE
    return (unsigned short)u;
}
DEVI float bf2f(unsigned v) { return __uint_as_float(v << 16); }

DEVI unsigned pkbf(float lo, float hi) {   // packed RNE f32->bf16 pair
    unsigned r;
    asm("v_cvt_pk_bf16_f32 %0, %1, %2" : "=v"(r) : "v"(lo), "v"(hi));
    return r;
}

// ---------- W_tok -> bf16^T, LDS-tiled: coalesced reads AND coalesced 512B writes ----------
__global__ __launch_bounds__(256) void k_trans(const float* __restrict__ W,
                                               unsigned short* __restrict__ wtb) {
    __shared__ unsigned short ldsT[32 * 264];
    const int t = threadIdx.x;
    const int k0 = (blockIdx.x >> 3) * 256;
    const int n0 = (blockIdx.x & 7) * 32;
    const int nn = t & 31, kk8 = t >> 5;
    #pragma unroll
    for (int r = 0; r < 32; ++r) {
        int k = r * 8 + kk8;
        ldsT[nn * 264 + k] = f2bf(W[(size_t)(k0 + k) * D_ + n0 + nn]);
    }
    __syncthreads();
    const int w = t >> 6, l = t & 63;
    #pragma unroll
    for (int rr = 0; rr < 8; ++rr) {
        int n = w * 8 + rr;
        ushort4 v = *(const ushort4*)(&ldsT[n * 264 + l * 4]);
        *(ushort4*)(wtb + (size_t)(n0 + n) * TOKD + k0 + l * 4) = v;
    }
}

// ---------- topk (blocks 0..799) + q-fold (800..807) ----------
__global__ __launch_bounds__(256) void k_topkqf(const float* __restrict__ act,
                                                int* __restrict__ oidx,
                                                float* __restrict__ asum,
                                                const float* __restrict__ pq,
                                                const float* __restrict__ Wq,
                                                const float* __restrict__ bqv,
                                                const float* __restrict__ Wk,
                                                const float* __restrict__ bkv,
                                                float* __restrict__ qW,
                                                float* __restrict__ qb) {
    __shared__ __align__(16) char smem[50304];
    const int t = threadIdx.x, lane = t & 63, wid = t >> 6;

    if (blockIdx.x >= 800) {
        float (*qpart)[32] = (float(*)[32])smem;
        float* qhl = (float*)(smem + 1024);
        const int h = blockIdx.x - 800;
        const int col = h * 32 + (t & 31), sl = t >> 5;
        float s = 0.f;
        #pragma unroll
        for (int e = 0; e < 32; ++e) s += pq[sl * 32 + e] * Wq[(sl * 32 + e) * D_ + col];
        qpart[sl][t & 31] = s;
        __syncthreads();
        if (t < 32) {
            float u = bqv[h * 32 + t];
            #pragma unroll
            for (int s8 = 0; s8 < 8; ++s8) u += qpart[s8][t];
            qhl[t] = u;
        }
        __syncthreads();
        float u = 0.f;
        #pragma unroll
        for (int dd = 0; dd < 32; ++dd) u += qhl[dd] * Wk[t * D_ + h * 32 + dd];
        qW[h * D_ + t] = u;
        if (t == 0) {
            float z = 0.f;
            for (int dd = 0; dd < 32; ++dd) z += qhl[dd] * bkv[h * 32 + dd];
            qb[h] = z;
        }
        return;
    }

    int* hist = (int*)smem;
    unsigned long long* cand = (unsigned long long*)(smem + 16384);
    int* csum = (int*)(smem + 49152);
    int* sb   = (int*)(smem + 50192);
    int* cnts = (int*)(smem + 50200);
    float* redf = (float*)(smem + 50208);
    unsigned long long* redu = (unsigned long long*)(smem + 50224);

    const int blk = blockIdx.x;
    const float* rp = act + (size_t)blk * N_;
    float fv[16]; unsigned vb[16]; int bins[16];
    float fs = 0.f;
    #pragma unroll
    for (int i = 0; i < 16; ++i) {
        float f = rp[t + i * 256];
        fv[i] = f; vb[i] = __float_as_uint(f);
        fs += f;
    }
    #pragma unroll
    for (int i = 0; i < 16; ++i) hist[t + i * 256] = 0;
    if (t == 0) { cnts[0] = 0; cnts[1] = 0; }
    #pragma unroll
    for (int m = 1; m < 64; m <<= 1) fs += __shfl_xor(fs, m);
    if (!lane) redf[wid] = fs;
    __syncthreads();
    if (t == 0) asum[blk] = fmaxf(redf[0] + redf[1] + redf[2] + redf[3], 1e-8f);

    #pragma unroll
    for (int i = 0; i < 16; ++i) {
        float f = fv[i];
        int b = (f >= 1.0f) ? 4095 : ((f > 0.f) ? (int)(f * 4096.f) : 0);
        bins[i] = b;
        atomicAdd(&hist[b], 1);
    }
    __syncthreads();

    int cs = 0;
    #pragma unroll
    for (int i = 0; i < 16; ++i) cs += hist[t * 16 + i];
    int v = cs;
    #pragma unroll
    for (int off = 1; off < 64; off <<= 1) {
        int o = __shfl_down(v, off);
        if (lane + off < 64) v += o;
    }
    if (!lane) csum[256 + wid] = v;
    __syncthreads();
    int stot = 0;
    for (int w2 = wid + 1; w2 < 4; ++w2) stot += csum[256 + w2];
    int suff = v + stot;
    csum[t] = suff;
    __syncthreads();
    int nxtc = (t < 255) ? csum[t + 1] : 0;
    if (suff >= K_ && nxtc < K_) {
        int run = nxtc, bstar = t * 16;
        for (int bi = 15; bi >= 0; --bi) {
            run += hist[t * 16 + bi];
            if (run >= K_) { bstar = t * 16 + bi; break; }
        }
        sb[0] = bstar;
    }
    __syncthreads();
    const int bstar = sb[0];

    #pragma unroll
    for (int i = 0; i < 16; ++i) {
        if (bins[i] > bstar) {
            int p = atomicAdd(&cnts[0], 1);
            oidx[blk * K_ + p] = t + i * 256;
        } else if (bins[i] == bstar) {
            int p = atomicAdd(&cnts[1], 1);
            cand[p] = ((unsigned long long)vb[i] << 16) | (unsigned)(4095 - (t + i * 256));
        }
    }
    __syncthreads();
    const int g = cnts[0], E = cnts[1], m = K_ - g;
    unsigned long long last = ~0ull;
    for (int slot = 0; slot < m; ++slot) {
        unsigned long long best = 0;
        for (int i = t; i < E; i += 256) {
            unsigned long long e = cand[i];
            if (e < last && e > best) best = e;
        }
        #pragma unroll
        for (int mm = 1; mm < 64; mm <<= 1) {
            unsigned long long o = __shfl_xor(best, mm);
            if (o > best) best = o;
        }
        if (!lane) redu[wid] = best;
        __syncthreads();
        best = redu[0];
        if (redu[1] > best) best = redu[1];
        if (redu[2] > best) best = redu[2];
        if (redu[3] > best) best = redu[3];
        if (t == 0) oidx[blk * K_ + g + slot] = 4095 - (int)(best & 0xFFFFull);
        last = best;
        __syncthreads();
    }
}

// ---------- GEMM1 + bias + LN fused: 32x256 tile, BK=32, 1024 blocks = 3 blocks/CU ----------
// All reg-staged (A 128B-runs waves 0-3 only, B 64B-runs), padded 80B LDS rows.
// Per-iter sync = lgkmcnt(0) + raw s_barrier: vmem prefetch stays in flight.
__global__ __launch_bounds__(512, 4) void k_gemm1(const float* __restrict__ A,
                                                  const unsigned short* __restrict__ Bt,
                                                  const float* __restrict__ btok,
                                                  const float* __restrict__ g,
                                                  const float* __restrict__ bt,
                                                  unsigned short* __restrict__ tp) {
    // A bufs: 2 x 2560 B @ [0,5120); B bufs: 2 x 20480 B @ [5120,46080). Epilogue 33.3KB reuses.
    __shared__ __align__(16) char smem[46080];
    const int t = threadIdx.x;
    const int bm = blockIdx.x;
    const int lane = t & 63, w = t >> 6;
    const int wm = w >> 2, wn = w & 3;       // 2x4 waves, wave tile 16x64
    const int lr = lane >> 4, lc = lane & 15;
    const int NT = TOKD / 32;                // 64

    // A staging (waves 0-3 only; wave-uniform guard): row = t>>3, k-off (t&7)*4 f32
    const bool ast = (t < 256);
    const float* agp = A + (size_t)(bm * 32 + ((t >> 3) & 31)) * TOKD + (t & 7) * 4;
    const int awo = (t >> 3) * 80 + (t & 7) * 8;
    // B staging: n = t>>1, k-half (t&1)*16 bf16 -> 64B runs per n
    const unsigned short* bgp = Bt + (size_t)(t >> 1) * TOKD + (t & 1) * 16;
    const int bwo = (t >> 1) * 80 + (t & 1) * 32;
    // fragment read offsets (padded rows)
    const int aro = (wm * 16 + lc) * 80 + lr * 16;
    const int bro = (wn * 64 + lc) * 80 + lr * 16;   // + ni*16*80

    f32x4 acc[4] = {};
    float4 ta = {0.f, 0.f, 0.f, 0.f};
    uint4 tb0, tb1;

    // ---- prologue: stage tile 0, prefetch tile 1 into regs
    if (ast) ta = *(const float4*)(agp);
    tb0 = *(const uint4*)(bgp);
    tb1 = *(const uint4*)(bgp + 8);
    if (ast) {
        uint2 v; v.x = pkbf(ta.x, ta.y); v.y = pkbf(ta.z, ta.w);
        *(uint2*)(smem + awo) = v;
    }
    *(uint4*)(smem + 5120 + bwo) = tb0;
    *(uint4*)(smem + 5120 + bwo + 16) = tb1;
    if (ast) ta = *(const float4*)(agp + 32);
    tb0 = *(const uint4*)(bgp + 32);
    tb1 = *(const uint4*)(bgp + 40);
    __syncthreads();

    for (int kt = 0; kt < NT; ++kt) {
        const int cur = kt & 1, nxt = cur ^ 1;
        const char* Ab = smem + cur * 2560;
        const char* Bb = smem + 5120 + cur * 20480;
        short8 afr = *(const short8*)(Ab + aro);
        short8 bfr0 = *(const short8*)(Bb + bro);
        short8 bfr1 = *(const short8*)(Bb + bro + 16 * 80);
        short8 bfr2 = *(const short8*)(Bb + bro + 32 * 80);
        short8 bfr3 = *(const short8*)(Bb + bro + 48 * 80);
        __builtin_amdgcn_s_setprio(1);
        acc[0] = __builtin_amdgcn_mfma_f32_16x16x32_bf16(afr, bfr0, acc[0], 0, 0, 0);
        acc[1] = __builtin_amdgcn_mfma_f32_16x16x32_bf16(afr, bfr1, acc[1], 0, 0, 0);
        acc[2] = __builtin_amdgcn_mfma_f32_16x16x32_bf16(afr, bfr2, acc[2], 0, 0, 0);
        acc[3] = __builtin_amdgcn_mfma_f32_16x16x32_bf16(afr, bfr3, acc[3], 0, 0, 0);
        __builtin_amdgcn_s_setprio(0);
        if (kt + 1 < NT) {
            if (ast) {
                uint2 v; v.x = pkbf(ta.x, ta.y); v.y = pkbf(ta.z, ta.w);
                *(uint2*)(smem + nxt * 2560 + awo) = v;
            }
            *(uint4*)(smem + 5120 + nxt * 20480 + bwo) = tb0;
            *(uint4*)(smem + 5120 + nxt * 20480 + bwo + 16) = tb1;
            if (kt + 2 < NT) {
                if (ast) ta = *(const float4*)(agp + (kt + 2) * 32);
                tb0 = *(const uint4*)(bgp + (kt + 2) * 32);
                tb1 = *(const uint4*)(bgp + (kt + 2) * 32 + 8);
            }
            asm volatile("s_waitcnt lgkmcnt(0)" ::: "memory");
            __builtin_amdgcn_s_barrier();
        }
    }
    __syncthreads();

    // ---- fused epilogue: bias + LN + bf16 store (32 rows x 260 f32 = 33.3 KB)
    float* ep = (float*)smem;
    const int col0 = lane * 4;
    float4 b4 = *(const float4*)(btok + col0);
    float4 g4 = *(const float4*)(g + col0);
    float4 t4 = *(const float4*)(bt + col0);
    #pragma unroll
    for (int ni = 0; ni < 4; ++ni)
        #pragma unroll
        for (int r = 0; r < 4; ++r)
            ep[(wm * 16 + lr * 4 + r) * 260 + wn * 64 + ni * 16 + lc] = acc[ni][r];
    __syncthreads();
    #pragma unroll
    for (int rr = 0; rr < 4; ++rr) {
        int row = w * 4 + rr;
        float4 x4 = *(const float4*)(ep + row * 260 + col0);
        float x0 = x4.x + b4.x, x1 = x4.y + b4.y, x2 = x4.z + b4.z, x3 = x4.w + b4.w;
        float s = x0 + x1 + x2 + x3;
        float q = x0*x0 + x1*x1 + x2*x2 + x3*x3;
        #pragma unroll
        for (int m = 1; m < 64; m <<= 1) { s += __shfl_xor(s, m); q += __shfl_xor(q, m); }
        float mean = s * (1.f/256.f);
        float var = q * (1.f/256.f) - mean * mean;
        float rs = rsqrtf(var + 1e-5f);
        ushort4 o;
        o.x = f2bf((x0-mean)*rs*g4.x + t4.x);
        o.y = f2bf((x1-mean)*rs*g4.y + t4.y);
        o.z = f2bf((x2-mean)*rs*g4.z + t4.z);
        o.w = f2bf((x3-mean)*rs*g4.w + t4.w);
        *(ushort4*)(tp + (size_t)(bm * 32 + row) * D_ + col0) = o;
    }
}

// ---------- weighted-average partials (grid z-split x5) ----------
__global__ __launch_bounds__(256) void k_wavg(const float* __restrict__ act,
                                              const unsigned short* __restrict__ tp,
                                              float* __restrict__ partial) {
    const int kc = blockIdx.x;
    const int b = blockIdx.y;
    const int d = threadIdx.x;
    const unsigned short* tpb = tp + ((size_t)b * N_ + kc * 128) * D_ + d;
    const float* actb = act + (size_t)b * O_ * N_ + kc * 128;
    float* pout = partial + ((size_t)(b * 32 + kc) * O_) * D_ + d;
    for (int oci = 0; oci < 2; ++oci) {
        const int oc = blockIdx.z * 2 + oci;
        float acc[10] = {};
        #pragma unroll 2
        for (int q = 0; q < 32; ++q) {
            float t0 = bf2f(tpb[(q * 4 + 0) * D_]);
            float t1 = bf2f(tpb[(q * 4 + 1) * D_]);
            float t2 = bf2f(tpb[(q * 4 + 2) * D_]);
            float t3 = bf2f(tpb[(q * 4 + 3) * D_]);
            #pragma unroll
            for (int oj = 0; oj < 10; ++oj) {
                float4 a4 = *(const float4*)(actb + (size_t)(oc * 10 + oj) * N_ + q * 4);
                acc[oj] += a4.x * t0 + a4.y * t1 + a4.z * t2 + a4.w * t3;
            }
        }
        #pragma unroll
        for (int oj = 0; oj < 10; ++oj)
            pout[(size_t)(oc * 10 + oj) * D_] = acc[oj];
    }
}

// ---------- attention v2: 2-pass tg (32KB), 37KB LDS -> 4 blocks/CU ----------
DEVI int swz64(int j, int chunk) { return j * 512 + ((chunk ^ (j & 31)) << 4); }

__global__ __launch_bounds__(256) void k_attn(
    const unsigned short* __restrict__ tp, const int* __restrict__ oidx,
    const float* __restrict__ qW, const float* __restrict__ qbv,
    const float* __restrict__ Wv, const float* __restrict__ bv,
    const float* __restrict__ Wo, const float* __restrict__ bo,
    const float* __restrict__ g_pn, const float* __restrict__ bt_pn,
    const float* __restrict__ g_on, const float* __restrict__ bt_on,
    const float* __restrict__ partial, const float* __restrict__ asum,
    float* __restrict__ outp)
{
    __shared__ __align__(16) char tg[32768];
    __shared__ float sc[H_ * K_];
    __shared__ float redf[8];
    __shared__ int idxl[K_];
    float* ul = (float*)tg;
    float* pool_lds = (float*)(tg + 8192);

    const int t = threadIdx.x, lane = t & 63, wid = t >> 6;
    const int blk = blockIdx.x;
    const int b = blk / O_;
    const int o = blk - b * O_;

    if (t < K_) idxl[t] = oidx[blk * K_ + t];
    __syncthreads();

    const int jq = t & 63, hp = t >> 6;
    const float* qr0 = qW + (hp * 2) * D_;
    const float* qr1 = qr0 + D_;
    const float sca = 0.1767766952966369f;

    for (int pass = 0; pass < 2; ++pass) {
        #pragma unroll
        for (int it = 0; it < 8; ++it) {
            int c = t + it * 256;
            int j = c >> 5, ch = c & 31;
            uint4 v = *(const uint4*)(tp + ((size_t)(b * N_ + idxl[pass * 64 + j])) * D_ + ch * 8);
            *(uint4*)(tg + swz64(j, ch)) = v;
        }
        __syncthreads();
        float s0 = 0.f, s1 = 0.f;
        #pragma unroll 4
        for (int e8 = 0; e8 < 32; ++e8) {
            uint4 tv = *(const uint4*)(tg + swz64(jq, e8));
            float f0 = bf2f(tv.x & 0xffffu), f1 = bf2f(tv.x >> 16);
            float f2 = bf2f(tv.y & 0xffffu), f3 = bf2f(tv.y >> 16);
            float f4 = bf2f(tv.z & 0xffffu), f5 = bf2f(tv.z >> 16);
            float f6 = bf2f(tv.w & 0xffffu), f7 = bf2f(tv.w >> 16);
            const float* qa = qr0 + e8 * 8;
            const float* qc = qr1 + e8 * 8;
            s0 += f0*qa[0]+f1*qa[1]+f2*qa[2]+f3*qa[3]+f4*qa[4]+f5*qa[5]+f6*qa[6]+f7*qa[7];
            s1 += f0*qc[0]+f1*qc[1]+f2*qc[2]+f3*qc[3]+f4*qc[4]+f5*qc[5]+f6*qc[6]+f7*qc[7];
        }
        sc[(hp * 2)     * K_ + pass * 64 + jq] = (s0 + qbv[hp * 2])     * sca;
        sc[(hp * 2 + 1) * K_ + pass * 64 + jq] = (s1 + qbv[hp * 2 + 1]) * sca;
        __syncthreads();
    }

    #pragma unroll
    for (int hh = 0; hh < 2; ++hh) {
        int h = wid * 2 + hh;
        float v0 = sc[h * K_ + lane], v1 = sc[h * K_ + 64 + lane];
        float mx = fmaxf(v0, v1);
        #pragma unroll
        for (int m = 1; m < 64; m <<= 1) mx = fmaxf(mx, __shfl_xor(mx, m));
        float e0 = __expf(v0 - mx), e1 = __expf(v1 - mx);
        float ss = e0 + e1;
        #pragma unroll
        for (int m = 1; m < 64; m <<= 1) ss += __shfl_xor(ss, m);
        float inv = 1.0f / ss;
        sc[h * K_ + lane] = e0 * inv;
        sc[h * K_ + 64 + lane] = e1 * inv;
    }
    __syncthreads();

    const int hq5 = t >> 5, eg = t & 31;
    float a8[8] = {};
    #pragma unroll 2
    for (int jb = 0; jb < 16; ++jb) {
        f32x4 p4 = *(const f32x4*)(sc + hq5 * K_ + 64 + jb * 4);
        #pragma unroll
        for (int ji = 0; ji < 4; ++ji) {
            int j = jb * 4 + ji;
            uint4 tv = *(const uint4*)(tg + swz64(j, eg));
            float pw = p4[ji];
            a8[0] += pw * bf2f(tv.x & 0xffffu); a8[1] += pw * bf2f(tv.x >> 16);
            a8[2] += pw * bf2f(tv.y & 0xffffu); a8[3] += pw * bf2f(tv.y >> 16);
            a8[4] += pw * bf2f(tv.z & 0xffffu); a8[5] += pw * bf2f(tv.z >> 16);
            a8[6] += pw * bf2f(tv.w & 0xffffu); a8[7] += pw * bf2f(tv.w >> 16);
        }
    }
    __syncthreads();
    #pragma unroll
    for (int it = 0; it < 8; ++it) {
        int c = t + it * 256;
        int j = c >> 5, ch = c & 31;
        uint4 v = *(const uint4*)(tp + ((size_t)(b * N_ + idxl[j])) * D_ + ch * 8);
        *(uint4*)(tg + swz64(j, ch)) = v;
    }
    __syncthreads();
    #pragma unroll 2
    for (int jb = 0; jb < 16; ++jb) {
        f32x4 p4 = *(const f32x4*)(sc + hq5 * K_ + jb * 4);
        #pragma unroll
        for (int ji = 0; ji < 4; ++ji) {
            int j = jb * 4 + ji;
            uint4 tv = *(const uint4*)(tg + swz64(j, eg));
            float pw = p4[ji];
            a8[0] += pw * bf2f(tv.x & 0xffffu); a8[1] += pw * bf2f(tv.x >> 16);
            a8[2] += pw * bf2f(tv.y & 0xffffu); a8[3] += pw * bf2f(tv.y >> 16);
            a8[4] += pw * bf2f(tv.z & 0xffffu); a8[5] += pw * bf2f(tv.z >> 16);
            a8[6] += pw * bf2f(tv.w & 0xffffu); a8[7] += pw * bf2f(tv.w >> 16);
        }
    }
    __syncthreads();
    #pragma unroll
    for (int i = 0; i < 8; ++i) ul[hq5 * D_ + eg * 8 + i] = a8[i];
    __syncthreads();

    {
        int h = t >> 5;
        const float* up = ul + h * D_;
        float p0 = 0.f, p1 = 0.f, p2 = 0.f, p3 = 0.f;
        #pragma unroll 4
        for (int e = 0; e < 64; ++e) {
            p0 += up[e]       * Wv[(size_t)e         * D_ + t];
            p1 += up[e + 64]  * Wv[(size_t)(e + 64)  * D_ + t];
            p2 += up[e + 128] * Wv[(size_t)(e + 128) * D_ + t];
            p3 += up[e + 192] * Wv[(size_t)(e + 192) * D_ + t];
        }
        pool_lds[t] = bv[t] + ((p0 + p1) + (p2 + p3));
    }
    __syncthreads();
    float po;
    {
        float p0 = 0.f, p1 = 0.f, p2 = 0.f, p3 = 0.f;
        #pragma unroll 4
        for (int e = 0; e < 64; ++e) {
            p0 += pool_lds[e]       * Wo[(size_t)e         * D_ + t];
            p1 += pool_lds[e + 64]  * Wo[(size_t)(e + 64)  * D_ + t];
            p2 += pool_lds[e + 128] * Wo[(size_t)(e + 128) * D_ + t];
            p3 += pool_lds[e + 192] * Wo[(size_t)(e + 192) * D_ + t];
        }
        po = bo[t] + ((p0 + p1) + (p2 + p3));
    }

    float lsm = po, lqm = po * po;
    #pragma unroll
    for (int m = 1; m < 64; m <<= 1) { lsm += __shfl_xor(lsm, m); lqm += __shfl_xor(lqm, m); }
    if (!lane) { redf[wid] = lsm; redf[4 + wid] = lqm; }
    __syncthreads();
    lsm = redf[0] + redf[1] + redf[2] + redf[3];
    lqm = redf[4] + redf[5] + redf[6] + redf[7];
    float mean = lsm * (1.f/256.f);
    float var = lqm * (1.f/256.f) - mean * mean;
    float rs = rsqrtf(var + 1e-5f);
    float pl = (po - mean) * rs * g_pn[t] + bt_pn[t];
    __syncthreads();

    float wa = 0.f;
    const float* pp = partial + ((size_t)(b * 32) * O_ + o) * D_ + t;
    #pragma unroll 8
    for (int kc = 0; kc < 32; ++kc) wa += pp[(size_t)kc * O_ * D_];
    float x = wa / asum[blk] + pl;
    float s2 = x, q2 = x * x;
    #pragma unroll
    for (int m = 1; m < 64; m <<= 1) { s2 += __shfl_xor(s2, m); q2 += __shfl_xor(q2, m); }
    if (!lane) { redf[wid] = s2; redf[4 + wid] = q2; }
    __syncthreads();
    s2 = redf[0] + redf[1] + redf[2] + redf[3];
    q2 = redf[4] + redf[5] + redf[6] + redf[7];
    float mean2 = s2 * (1.f/256.f);
    float var2 = q2 * (1.f/256.f) - mean2 * mean2;
    float rs2 = rsqrtf(var2 + 1e-5f);
    outp[(size_t)blk * D_ + t] = (x - mean2) * rs2 * g_on[t] + bt_on[t];
}

extern "C" void kernel_launch(void* const* d_in, const int* in_sizes, int n_in,
                              void* d_out, int out_size, void* d_ws, size_t ws_size,
                              hipStream_t stream) {
    const float* act    = (const float*)d_in[0];
    const float* tokens = (const float*)d_in[1];
    const float* W_tok  = (const float*)d_in[2];
    const float* b_tok  = (const float*)d_in[3];
    const float* g_tn   = (const float*)d_in[4];
    const float* bt_tn  = (const float*)d_in[5];
    const float* pq     = (const float*)d_in[6];
    const float* Wq     = (const float*)d_in[7];
    const float* bq     = (const float*)d_in[8];
    const float* Wk     = (const float*)d_in[9];
    const float* bk     = (const float*)d_in[10];
    const float* Wv     = (const float*)d_in[11];
    const float* bv     = (const float*)d_in[12];
    const float* Wo     = (const float*)d_in[13];
    const float* bo     = (const float*)d_in[14];
    const float* g_pn   = (const float*)d_in[15];
    const float* bt_pn  = (const float*)d_in[16];
    const float* g_on   = (const float*)d_in[17];
    const float* bt_on  = (const float*)d_in[18];

    char* ws = (char*)d_ws;
    unsigned short* wtb   = (unsigned short*)ws;                 // 1 MB
    unsigned short* tp    = (unsigned short*)(ws + 1048576);     // 16 MB
    int*   tidx = (int*)(ws + 17825792);                         // 409600
    float* asum = (float*)(ws + 18235392);                       // 3200
    float* part = (float*)(ws + 18238592);                       // 26.2 MB
    float* qW   = (float*)(ws + 44452992);                       // 8 KB
    float* qb   = (float*)(ws + 44461184);                       // 32 B

    k_trans<<<64, 256, 0, stream>>>(W_tok, wtb);
    k_gemm1<<<M_ / 32, 512, 0, stream>>>(tokens, wtb, b_tok, g_tn, bt_tn, tp);
    k_wavg<<<dim3(32, 8, 5), 256, 0, stream>>>(act, tp, part);
    k_topkqf<<<808, 256, 0, stream>>>(act, tidx, asum, pq, Wq, bq, Wk, bk, qW, qb);
    k_attn<<<B_ * O_, 256, 0, stream>>>(tp, tidx, qW, qb, Wv, bv, Wo, bo,
                                        g_pn, bt_pn, g_on, bt_on, part, asum,
                                        (float*)d_out);
}

// Round 15
// 249.518 us; speedup vs baseline: 1.1821x; 1.1821x over previous
//
#include <hip/hip_runtime.h>
#include <hip/hip_bf16.h>

#define DEVI static __device__ __forceinline__

typedef __attribute__((ext_vector_type(8))) short short8;
typedef __attribute__((ext_vector_type(4))) float f32x4;

#define B_   8
#define O_   100
#define N_   4096
#define TOKD 2048
#define D_   256
#define K_   128
#define H_   8
#define M_   (B_*N_)   // 32768

DEVI unsigned short f2bf(float f) {
    unsigned u = __float_as_uint(f);
    u = (u + 0x7FFFu + ((u >> 16) & 1u)) >> 16;   // RNE
    return (unsigned short)u;
}
DEVI float bf2f(unsigned v) { return __uint_as_float(v << 16); }

DEVI unsigned pkbf(float lo, float hi) {   // packed RNE f32->bf16 pair
    unsigned r;
    asm("v_cvt_pk_bf16_f32 %0, %1, %2" : "=v"(r) : "v"(lo), "v"(hi));
    return r;
}
DEVI void gload16(const void* g, void* l) {   // async global->LDS, 16B/lane
    __builtin_amdgcn_global_load_lds((const __attribute__((address_space(1))) void*)g,
                                     (__attribute__((address_space(3))) void*)l, 16, 0, 0);
}

// ---------- W_tok -> bf16^T, LDS-tiled ----------
__global__ __launch_bounds__(256) void k_trans(const float* __restrict__ W,
                                               unsigned short* __restrict__ wtb) {
    __shared__ unsigned short ldsT[32 * 264];
    const int t = threadIdx.x;
    const int k0 = (blockIdx.x >> 3) * 256;
    const int n0 = (blockIdx.x & 7) * 32;
    const int nn = t & 31, kk8 = t >> 5;
    #pragma unroll
    for (int r = 0; r < 32; ++r) {
        int k = r * 8 + kk8;
        ldsT[nn * 264 + k] = f2bf(W[(size_t)(k0 + k) * D_ + n0 + nn]);
    }
    __syncthreads();
    const int w = t >> 6, l = t & 63;
    #pragma unroll
    for (int rr = 0; rr < 8; ++rr) {
        int n = w * 8 + rr;
        ushort4 v = *(const ushort4*)(&ldsT[n * 264 + l * 4]);
        *(ushort4*)(wtb + (size_t)(n0 + n) * TOKD + k0 + l * 4) = v;
    }
}

// ---------- topk (blocks 0..799) + q-fold (800..807) ----------
__global__ __launch_bounds__(256) void k_topkqf(const float* __restrict__ act,
                                                int* __restrict__ oidx,
                                                float* __restrict__ asum,
                                                const float* __restrict__ pq,
                                                const float* __restrict__ Wq,
                                                const float* __restrict__ bqv,
                                                const float* __restrict__ Wk,
                                                const float* __restrict__ bkv,
                                                float* __restrict__ qW,
                                                float* __restrict__ qb) {
    __shared__ __align__(16) char smem[50304];
    const int t = threadIdx.x, lane = t & 63, wid = t >> 6;

    if (blockIdx.x >= 800) {
        float (*qpart)[32] = (float(*)[32])smem;
        float* qhl = (float*)(smem + 1024);
        const int h = blockIdx.x - 800;
        const int col = h * 32 + (t & 31), sl = t >> 5;
        float s = 0.f;
        #pragma unroll
        for (int e = 0; e < 32; ++e) s += pq[sl * 32 + e] * Wq[(sl * 32 + e) * D_ + col];
        qpart[sl][t & 31] = s;
        __syncthreads();
        if (t < 32) {
            float u = bqv[h * 32 + t];
            #pragma unroll
            for (int s8 = 0; s8 < 8; ++s8) u += qpart[s8][t];
            qhl[t] = u;
        }
        __syncthreads();
        float u = 0.f;
        #pragma unroll
        for (int dd = 0; dd < 32; ++dd) u += qhl[dd] * Wk[t * D_ + h * 32 + dd];
        qW[h * D_ + t] = u;
        if (t == 0) {
            float z = 0.f;
            for (int dd = 0; dd < 32; ++dd) z += qhl[dd] * bkv[h * 32 + dd];
            qb[h] = z;
        }
        return;
    }

    int* hist = (int*)smem;
    unsigned long long* cand = (unsigned long long*)(smem + 16384);
    int* csum = (int*)(smem + 49152);
    int* sb   = (int*)(smem + 50192);
    int* cnts = (int*)(smem + 50200);
    float* redf = (float*)(smem + 50208);
    unsigned long long* redu = (unsigned long long*)(smem + 50224);

    const int blk = blockIdx.x;
    const float* rp = act + (size_t)blk * N_;
    float fv[16]; unsigned vb[16]; int bins[16];
    float fs = 0.f;
    #pragma unroll
    for (int i = 0; i < 16; ++i) {
        float f = rp[t + i * 256];
        fv[i] = f; vb[i] = __float_as_uint(f);
        fs += f;
    }
    #pragma unroll
    for (int i = 0; i < 16; ++i) hist[t + i * 256] = 0;
    if (t == 0) { cnts[0] = 0; cnts[1] = 0; }
    #pragma unroll
    for (int m = 1; m < 64; m <<= 1) fs += __shfl_xor(fs, m);
    if (!lane) redf[wid] = fs;
    __syncthreads();
    if (t == 0) asum[blk] = fmaxf(redf[0] + redf[1] + redf[2] + redf[3], 1e-8f);

    #pragma unroll
    for (int i = 0; i < 16; ++i) {
        float f = fv[i];
        int b = (f >= 1.0f) ? 4095 : ((f > 0.f) ? (int)(f * 4096.f) : 0);
        bins[i] = b;
        atomicAdd(&hist[b], 1);
    }
    __syncthreads();

    int cs = 0;
    #pragma unroll
    for (int i = 0; i < 16; ++i) cs += hist[t * 16 + i];
    int v = cs;
    #pragma unroll
    for (int off = 1; off < 64; off <<= 1) {
        int o = __shfl_down(v, off);
        if (lane + off < 64) v += o;
    }
    if (!lane) csum[256 + wid] = v;
    __syncthreads();
    int stot = 0;
    for (int w2 = wid + 1; w2 < 4; ++w2) stot += csum[256 + w2];
    int suff = v + stot;
    csum[t] = suff;
    __syncthreads();
    int nxtc = (t < 255) ? csum[t + 1] : 0;
    if (suff >= K_ && nxtc < K_) {
        int run = nxtc, bstar = t * 16;
        for (int bi = 15; bi >= 0; --bi) {
            run += hist[t * 16 + bi];
            if (run >= K_) { bstar = t * 16 + bi; break; }
        }
        sb[0] = bstar;
    }
    __syncthreads();
    const int bstar = sb[0];

    #pragma unroll
    for (int i = 0; i < 16; ++i) {
        if (bins[i] > bstar) {
            int p = atomicAdd(&cnts[0], 1);
            oidx[blk * K_ + p] = t + i * 256;
        } else if (bins[i] == bstar) {
            int p = atomicAdd(&cnts[1], 1);
            cand[p] = ((unsigned long long)vb[i] << 16) | (unsigned)(4095 - (t + i * 256));
        }
    }
    __syncthreads();
    const int g = cnts[0], E = cnts[1], m = K_ - g;
    unsigned long long last = ~0ull;
    for (int slot = 0; slot < m; ++slot) {
        unsigned long long best = 0;
        for (int i = t; i < E; i += 256) {
            unsigned long long e = cand[i];
            if (e < last && e > best) best = e;
        }
        #pragma unroll
        for (int mm = 1; mm < 64; mm <<= 1) {
            unsigned long long o = __shfl_xor(best, mm);
            if (o > best) best = o;
        }
        if (!lane) redu[wid] = best;
        __syncthreads();
        best = redu[0];
        if (redu[1] > best) best = redu[1];
        if (redu[2] > best) best = redu[2];
        if (redu[3] > best) best = redu[3];
        if (t == 0) oidx[blk * K_ + g + slot] = 4095 - (int)(best & 0xFFFFull);
        last = best;
        __syncthreads();
    }
}

// ---------- GEMM1 + bias + LN fused: 64x256, BK=32, counted-vmcnt pipeline, 2 blk/CU ----------
// A: [ko4][row64][16B] dbuf (conflict-free), reg-staged by waves 0-3, depth-2.
// B: [n256][64B] XOR((n&3)<<4) tribuf via gload_lds, depth-2; never drain mid-loop.
// Key: A-loads issued BEFORE B-issue each iter -> A-write's implicit vmcnt keeps B(kt+1) in flight.
#define GSTEP(KT, ACUR, ANXT, RLOAD, RWRITE)                                                     \
    {                                                                                            \
        if (ast && (KT) + 2 < NT) {                                                              \
            RLOAD[0] = *(const float4*)(agp + ((KT) + 2) * 32);                                  \
            RLOAD[1] = *(const float4*)(agp + ((KT) + 2) * 32 + 4);                              \
        }                                                                                        \
        if ((KT) + 2 < NT) {                                                                     \
            gload16(bg0 + ((KT) + 2) * 32, bnx + bd0);                                           \
            gload16(bg1 + ((KT) + 2) * 32, bnx + bd1);                                           \
        }                                                                                        \
        {                                                                                        \
            short8 af0 = *(const short8*)((ACUR) + aro);                                         \
            short8 af1 = *(const short8*)((ACUR) + aro + 256);                                   \
            short8 bf0 = *(const short8*)(bcu + bro);                                            \
            short8 bf1 = *(const short8*)(bcu + bro + 1024);                                     \
            short8 bf2 = *(const short8*)(bcu + bro + 2048);                                     \
            short8 bf3 = *(const short8*)(bcu + bro + 3072);                                     \
            __builtin_amdgcn_s_setprio(1);                                                       \
            acc[0][0] = __builtin_amdgcn_mfma_f32_16x16x32_bf16(af0, bf0, acc[0][0], 0, 0, 0);   \
            acc[0][1] = __builtin_amdgcn_mfma_f32_16x16x32_bf16(af0, bf1, acc[0][1], 0, 0, 0);   \
            acc[0][2] = __builtin_amdgcn_mfma_f32_16x16x32_bf16(af0, bf2, acc[0][2], 0, 0, 0);   \
            acc[0][3] = __builtin_amdgcn_mfma_f32_16x16x32_bf16(af0, bf3, acc[0][3], 0, 0, 0);   \
            acc[1][0] = __builtin_amdgcn_mfma_f32_16x16x32_bf16(af1, bf0, acc[1][0], 0, 0, 0);   \
            acc[1][1] = __builtin_amdgcn_mfma_f32_16x16x32_bf16(af1, bf1, acc[1][1], 0, 0, 0);   \
            acc[1][2] = __builtin_amdgcn_mfma_f32_16x16x32_bf16(af1, bf2, acc[1][2], 0, 0, 0);   \
            acc[1][3] = __builtin_amdgcn_mfma_f32_16x16x32_bf16(af1, bf3, acc[1][3], 0, 0, 0);   \
            __builtin_amdgcn_s_setprio(0);                                                       \
        }                                                                                        \
        if (ast && (KT) + 1 < NT) {                                                              \
            uint4 v;                                                                             \
            v.x = pkbf(RWRITE[0].x, RWRITE[0].y); v.y = pkbf(RWRITE[0].z, RWRITE[0].w);          \
            v.z = pkbf(RWRITE[1].x, RWRITE[1].y); v.w = pkbf(RWRITE[1].z, RWRITE[1].w);          \
            *(uint4*)((ANXT) + awo) = v;                                                         \
        }                                                                                        \
        if ((KT) + 1 < NT) {                                                                     \
            if ((KT) < NT - 3) {                                                                 \
                if (ast) asm volatile("s_waitcnt vmcnt(4)" ::: "memory");                        \
                else     asm volatile("s_waitcnt vmcnt(2)" ::: "memory");                        \
            } else {                                                                             \
                asm volatile("s_waitcnt vmcnt(0)" ::: "memory");                                 \
            }                                                                                    \
            asm volatile("s_waitcnt lgkmcnt(0)" ::: "memory");                                   \
            __builtin_amdgcn_s_barrier();                                                        \
        }                                                                                        \
        { char* tmp_ = bcu; bcu = bn1; bn1 = bnx; bnx = tmp_; }                                  \
    }

__global__ __launch_bounds__(512, 4) void k_gemm1(const float* __restrict__ A,
                                                  const unsigned short* __restrict__ Bt,
                                                  const float* __restrict__ btok,
                                                  const float* __restrict__ g,
                                                  const float* __restrict__ bt,
                                                  unsigned short* __restrict__ tp) {
    // A bufs 2x4KB [0,8192); B bufs 3x16KB [8192,57344). Epilogue 33.3KB reuses [0,..).
    __shared__ __align__(16) char smem[57344];
    const int t = threadIdx.x;
    const int bm = blockIdx.x;
    const int lane = t & 63, w = t >> 6;
    const int wm = w >> 2, wn = w & 3;       // 2x4 waves, wave tile 32x64
    const int lr = lane >> 4, lc = lane & 15;
    const int NT = TOKD / 32;                // 64

    // A staging (waves 0-3): row = t>>2, ko = t&3; 8 f32 -> 16B bf16; 128B global runs
    const bool ast = (t < 256);
    const float* agp = A + (size_t)(bm * 64 + ((t >> 2) & 63)) * TOKD + (t & 3) * 8;
    const int awo = (t & 3) * 1024 + ((t >> 2) & 63) * 16;
    // B staging: slot idx i = w*128 + {0,64} + lane; n = i>>2, sl = i&3 (src pre-XOR'd)
    const int i0 = w * 128 + lane, i1 = i0 + 64;
    const unsigned short* bg0 = Bt + (size_t)(i0 >> 2) * TOKD + (((((i0 & 3) << 4)) ^ (((i0 >> 2) & 3) << 4)) >> 1);
    const unsigned short* bg1 = Bt + (size_t)(i1 >> 2) * TOKD + (((((i1 & 3) << 4)) ^ (((i1 >> 2) & 3) << 4)) >> 1);
    const int bd0 = (w * 2 + 0) * 1024;      // wave-uniform LDS dst bases
    const int bd1 = (w * 2 + 1) * 1024;
    // fragment read offsets
    const int aro = lr * 1024 + (wm * 32 + lc) * 16;           // + mi*256
    const int bro = (wn * 64 + lc) * 64 + ((lr * 16) ^ ((lc & 3) << 4));   // + ni*1024

    f32x4 acc[2][4] = {};
    float4 ra0[2], ra1[2];
    char* Abuf0 = smem;
    char* Abuf1 = smem + 4096;
    char* bcu = smem + 8192;
    char* bn1 = smem + 8192 + 16384;
    char* bnx = smem + 8192 + 32768;

    // ---- prologue: A(0)->ra0, B(0); A(1)->ra1, B(1); write A(0); retire B(0) only
    if (ast) { ra0[0] = *(const float4*)(agp); ra0[1] = *(const float4*)(agp + 4); }
    gload16(bg0, bcu + bd0); gload16(bg1, bcu + bd1);
    if (ast) { ra1[0] = *(const float4*)(agp + 32); ra1[1] = *(const float4*)(agp + 36); }
    gload16(bg0 + 32, bn1 + bd0); gload16(bg1 + 32, bn1 + bd1);
    if (ast) {
        uint4 v;
        v.x = pkbf(ra0[0].x, ra0[0].y); v.y = pkbf(ra0[0].z, ra0[0].w);
        v.z = pkbf(ra0[1].x, ra0[1].y); v.w = pkbf(ra0[1].z, ra0[1].w);
        *(uint4*)(Abuf0 + awo) = v;
        asm volatile("s_waitcnt vmcnt(4)" ::: "memory");   // keep A(1)+B(1)
    } else {
        asm volatile("s_waitcnt vmcnt(2)" ::: "memory");   // keep B(1)
    }
    asm volatile("s_waitcnt lgkmcnt(0)" ::: "memory");
    __builtin_amdgcn_s_barrier();

    for (int kt = 0; kt < NT; kt += 2) {
        GSTEP(kt,     Abuf0, Abuf1, ra0, ra1)   // load A(kt+2)->ra0, write A(kt+1) from ra1
        GSTEP(kt + 1, Abuf1, Abuf0, ra1, ra0)   // load A(kt+3)->ra1, write A(kt+2) from ra0
    }
    __syncthreads();

    // ---- fused epilogue: bias + LN + bf16 store, 2 chunks of 32 rows (32x260 f32)
    float* ep = (float*)smem;
    const int col0 = lane * 4;
    float4 b4 = *(const float4*)(btok + col0);
    float4 g4 = *(const float4*)(g + col0);
    float4 t4 = *(const float4*)(bt + col0);
    #pragma unroll
    for (int c = 0; c < 2; ++c) {
        if (wm == c) {
            #pragma unroll
            for (int mi = 0; mi < 2; ++mi)
                #pragma unroll
                for (int ni = 0; ni < 4; ++ni)
                    #pragma unroll
                    for (int r = 0; r < 4; ++r)
                        ep[(mi * 16 + lr * 4 + r) * 260 + wn * 64 + ni * 16 + lc] = acc[mi][ni][r];
        }
        __syncthreads();
        #pragma unroll
        for (int rr = 0; rr < 4; ++rr) {
            int row = w * 4 + rr;
            float4 x4 = *(const float4*)(ep + row * 260 + col0);
            float x0 = x4.x + b4.x, x1 = x4.y + b4.y, x2 = x4.z + b4.z, x3 = x4.w + b4.w;
            float s = x0 + x1 + x2 + x3;
            float q = x0*x0 + x1*x1 + x2*x2 + x3*x3;
            #pragma unroll
            for (int m = 1; m < 64; m <<= 1) { s += __shfl_xor(s, m); q += __shfl_xor(q, m); }
            float mean = s * (1.f/256.f);
            float var = q * (1.f/256.f) - mean * mean;
            float rs = rsqrtf(var + 1e-5f);
            ushort4 o;
            o.x = f2bf((x0-mean)*rs*g4.x + t4.x);
            o.y = f2bf((x1-mean)*rs*g4.y + t4.y);
            o.z = f2bf((x2-mean)*rs*g4.z + t4.z);
            o.w = f2bf((x3-mean)*rs*g4.w + t4.w);
            *(ushort4*)(tp + (size_t)(bm * 64 + c * 32 + row) * D_ + col0) = o;
        }
        __syncthreads();
    }
}

// ---------- weighted-average partials (grid z-split x5) ----------
__global__ __launch_bounds__(256) void k_wavg(const float* __restrict__ act,
                                              const unsigned short* __restrict__ tp,
                                              float* __restrict__ partial) {
    const int kc = blockIdx.x;
    const int b = blockIdx.y;
    const int d = threadIdx.x;
    const unsigned short* tpb = tp + ((size_t)b * N_ + kc * 128) * D_ + d;
    const float* actb = act + (size_t)b * O_ * N_ + kc * 128;
    float* pout = partial + ((size_t)(b * 32 + kc) * O_) * D_ + d;
    for (int oci = 0; oci < 2; ++oci) {
        const int oc = blockIdx.z * 2 + oci;
        float acc[10] = {};
        #pragma unroll 2
        for (int q = 0; q < 32; ++q) {
            float t0 = bf2f(tpb[(q * 4 + 0) * D_]);
            float t1 = bf2f(tpb[(q * 4 + 1) * D_]);
            float t2 = bf2f(tpb[(q * 4 + 2) * D_]);
            float t3 = bf2f(tpb[(q * 4 + 3) * D_]);
            #pragma unroll
            for (int oj = 0; oj < 10; ++oj) {
                float4 a4 = *(const float4*)(actb + (size_t)(oc * 10 + oj) * N_ + q * 4);
                acc[oj] += a4.x * t0 + a4.y * t1 + a4.z * t2 + a4.w * t3;
            }
        }
        #pragma unroll
        for (int oj = 0; oj < 10; ++oj)
            pout[(size_t)(oc * 10 + oj) * D_] = acc[oj];
    }
}

// ---------- attention v2: 2-pass tg (32KB), 37KB LDS -> 4 blocks/CU ----------
DEVI int swz64(int j, int chunk) { return j * 512 + ((chunk ^ (j & 31)) << 4); }

__global__ __launch_bounds__(256) void k_attn(
    const unsigned short* __restrict__ tp, const int* __restrict__ oidx,
    const float* __restrict__ qW, const float* __restrict__ qbv,
    const float* __restrict__ Wv, const float* __restrict__ bv,
    const float* __restrict__ Wo, const float* __restrict__ bo,
    const float* __restrict__ g_pn, const float* __restrict__ bt_pn,
    const float* __restrict__ g_on, const float* __restrict__ bt_on,
    const float* __restrict__ partial, const float* __restrict__ asum,
    float* __restrict__ outp)
{
    __shared__ __align__(16) char tg[32768];
    __shared__ float sc[H_ * K_];
    __shared__ float redf[8];
    __shared__ int idxl[K_];
    float* ul = (float*)tg;
    float* pool_lds = (float*)(tg + 8192);

    const int t = threadIdx.x, lane = t & 63, wid = t >> 6;
    const int blk = blockIdx.x;
    const int b = blk / O_;
    const int o = blk - b * O_;

    if (t < K_) idxl[t] = oidx[blk * K_ + t];
    __syncthreads();

    const int jq = t & 63, hp = t >> 6;
    const float* qr0 = qW + (hp * 2) * D_;
    const float* qr1 = qr0 + D_;
    const float sca = 0.1767766952966369f;

    for (int pass = 0; pass < 2; ++pass) {
        #pragma unroll
        for (int it = 0; it < 8; ++it) {
            int c = t + it * 256;
            int j = c >> 5, ch = c & 31;
            uint4 v = *(const uint4*)(tp + ((size_t)(b * N_ + idxl[pass * 64 + j])) * D_ + ch * 8);
            *(uint4*)(tg + swz64(j, ch)) = v;
        }
        __syncthreads();
        float s0 = 0.f, s1 = 0.f;
        #pragma unroll 4
        for (int e8 = 0; e8 < 32; ++e8) {
            uint4 tv = *(const uint4*)(tg + swz64(jq, e8));
            float f0 = bf2f(tv.x & 0xffffu), f1 = bf2f(tv.x >> 16);
            float f2 = bf2f(tv.y & 0xffffu), f3 = bf2f(tv.y >> 16);
            float f4 = bf2f(tv.z & 0xffffu), f5 = bf2f(tv.z >> 16);
            float f6 = bf2f(tv.w & 0xffffu), f7 = bf2f(tv.w >> 16);
            const float* qa = qr0 + e8 * 8;
            const float* qc = qr1 + e8 * 8;
            s0 += f0*qa[0]+f1*qa[1]+f2*qa[2]+f3*qa[3]+f4*qa[4]+f5*qa[5]+f6*qa[6]+f7*qa[7];
            s1 += f0*qc[0]+f1*qc[1]+f2*qc[2]+f3*qc[3]+f4*qc[4]+f5*qc[5]+f6*qc[6]+f7*qc[7];
        }
        sc[(hp * 2)     * K_ + pass * 64 + jq] = (s0 + qbv[hp * 2])     * sca;
        sc[(hp * 2 + 1) * K_ + pass * 64 + jq] = (s1 + qbv[hp * 2 + 1]) * sca;
        __syncthreads();
    }

    #pragma unroll
    for (int hh = 0; hh < 2; ++hh) {
        int h = wid * 2 + hh;
        float v0 = sc[h * K_ + lane], v1 = sc[h * K_ + 64 + lane];
        float mx = fmaxf(v0, v1);
        #pragma unroll
        for (int m = 1; m < 64; m <<= 1) mx = fmaxf(mx, __shfl_xor(mx, m));
        float e0 = __expf(v0 - mx), e1 = __expf(v1 - mx);
        float ss = e0 + e1;
        #pragma unroll
        for (int m = 1; m < 64; m <<= 1) ss += __shfl_xor(ss, m);
        float inv = 1.0f / ss;
        sc[h * K_ + lane] = e0 * inv;
        sc[h * K_ + 64 + lane] = e1 * inv;
    }
    __syncthreads();

    const int hq5 = t >> 5, eg = t & 31;
    float a8[8] = {};
    #pragma unroll 2
    for (int jb = 0; jb < 16; ++jb) {
        f32x4 p4 = *(const f32x4*)(sc + hq5 * K_ + 64 + jb * 4);
        #pragma unroll
        for (int ji = 0; ji < 4; ++ji) {
            int j = jb * 4 + ji;
            uint4 tv = *(const uint4*)(tg + swz64(j, eg));
            float pw = p4[ji];
            a8[0] += pw * bf2f(tv.x & 0xffffu); a8[1] += pw * bf2f(tv.x >> 16);
            a8[2] += pw * bf2f(tv.y & 0xffffu); a8[3] += pw * bf2f(tv.y >> 16);
            a8[4] += pw * bf2f(tv.z & 0xffffu); a8[5] += pw * bf2f(tv.z >> 16);
            a8[6] += pw * bf2f(tv.w & 0xffffu); a8[7] += pw * bf2f(tv.w >> 16);
        }
    }
    __syncthreads();
    #pragma unroll
    for (int it = 0; it < 8; ++it) {
        int c = t + it * 256;
        int j = c >> 5, ch = c & 31;
        uint4 v = *(const uint4*)(tp + ((size_t)(b * N_ + idxl[j])) * D_ + ch * 8);
        *(uint4*)(tg + swz64(j, ch)) = v;
    }
    __syncthreads();
    #pragma unroll 2
    for (int jb = 0; jb < 16; ++jb) {
        f32x4 p4 = *(const f32x4*)(sc + hq5 * K_ + jb * 4);
        #pragma unroll
        for (int ji = 0; ji < 4; ++ji) {
            int j = jb * 4 + ji;
            uint4 tv = *(const uint4*)(tg + swz64(j, eg));
            float pw = p4[ji];
            a8[0] += pw * bf2f(tv.x & 0xffffu); a8[1] += pw * bf2f(tv.x >> 16);
            a8[2] += pw * bf2f(tv.y & 0xffffu); a8[3] += pw * bf2f(tv.y >> 16);
            a8[4] += pw * bf2f(tv.z & 0xffffu); a8[5] += pw * bf2f(tv.z >> 16);
            a8[6] += pw * bf2f(tv.w & 0xffffu); a8[7] += pw * bf2f(tv.w >> 16);
        }
    }
    __syncthreads();
    #pragma unroll
    for (int i = 0; i < 8; ++i) ul[hq5 * D_ + eg * 8 + i] = a8[i];
    __syncthreads();

    {
        int h = t >> 5;
        const float* up = ul + h * D_;
        float p0 = 0.f, p1 = 0.f, p2 = 0.f, p3 = 0.f;
        #pragma unroll 4
        for (int e = 0; e < 64; ++e) {
            p0 += up[e]       * Wv[(size_t)e         * D_ + t];
            p1 += up[e + 64]  * Wv[(size_t)(e + 64)  * D_ + t];
            p2 += up[e + 128] * Wv[(size_t)(e + 128) * D_ + t];
            p3 += up[e + 192] * Wv[(size_t)(e + 192) * D_ + t];
        }
        pool_lds[t] = bv[t] + ((p0 + p1) + (p2 + p3));
    }
    __syncthreads();
    float po;
    {
        float p0 = 0.f, p1 = 0.f, p2 = 0.f, p3 = 0.f;
        #pragma unroll 4
        for (int e = 0; e < 64; ++e) {
            p0 += pool_lds[e]       * Wo[(size_t)e         * D_ + t];
            p1 += pool_lds[e + 64]  * Wo[(size_t)(e + 64)  * D_ + t];
            p2 += pool_lds[e + 128] * Wo[(size_t)(e + 128) * D_ + t];
            p3 += pool_lds[e + 192] * Wo[(size_t)(e + 192) * D_ + t];
        }
        po = bo[t] + ((p0 + p1) + (p2 + p3));
    }

    float lsm = po, lqm = po * po;
    #pragma unroll
    for (int m = 1; m < 64; m <<= 1) { lsm += __shfl_xor(lsm, m); lqm += __shfl_xor(lqm, m); }
    if (!lane) { redf[wid] = lsm; redf[4 + wid] = lqm; }
    __syncthreads();
    lsm = redf[0] + redf[1] + redf[2] + redf[3];
    lqm = redf[4] + redf[5] + redf[6] + redf[7];
    float mean = lsm * (1.f/256.f);
    float var = lqm * (1.f/256.f) - mean * mean;
    float rs = rsqrtf(var + 1e-5f);
    float pl = (po - mean) * rs * g_pn[t] + bt_pn[t];
    __syncthreads();

    float wa = 0.f;
    const float* pp = partial + ((size_t)(b * 32) * O_ + o) * D_ + t;
    #pragma unroll 8
    for (int kc = 0; kc < 32; ++kc) wa += pp[(size_t)kc * O_ * D_];
    float x = wa / asum[blk] + pl;
    float s2 = x, q2 = x * x;
    #pragma unroll
    for (int m = 1; m < 64; m <<= 1) { s2 += __shfl_xor(s2, m); q2 += __shfl_xor(q2, m); }
    if (!lane) { redf[wid] = s2; redf[4 + wid] = q2; }
    __syncthreads();
    s2 = redf[0] + redf[1] + redf[2] + redf[3];
    q2 = redf[4] + redf[5] + redf[6] + redf[7];
    float mean2 = s2 * (1.f/256.f);
    float var2 = q2 * (1.f/256.f) - mean2 * mean2;
    float rs2 = rsqrtf(var2 + 1e-5f);
    outp[(size_t)blk * D_ + t] = (x - mean2) * rs2 * g_on[t] + bt_on[t];
}

extern "C" void kernel_launch(void* const* d_in, const int* in_sizes, int n_in,
                              void* d_out, int out_size, void* d_ws, size_t ws_size,
                              hipStream_t stream) {
    const float* act    = (const float*)d_in[0];
    const float* tokens = (const float*)d_in[1];
    const float* W_tok  = (const float*)d_in[2];
    const float* b_tok  = (const float*)d_in[3];
    const float* g_tn   = (const float*)d_in[4];
    const float* bt_tn  = (const float*)d_in[5];
    const float* pq     = (const float*)d_in[6];
    const float* Wq     = (const float*)d_in[7];
    const float* bq     = (const float*)d_in[8];
    const float* Wk     = (const float*)d_in[9];
    const float* bk     = (const float*)d_in[10];
    const float* Wv     = (const float*)d_in[11];
    const float* bv     = (const float*)d_in[12];
    const float* Wo     = (const float*)d_in[13];
    const float* bo     = (const float*)d_in[14];
    const float* g_pn   = (const float*)d_in[15];
    const float* bt_pn  = (const float*)d_in[16];
    const float* g_on   = (const float*)d_in[17];
    const float* bt_on  = (const float*)d_in[18];

    char* ws = (char*)d_ws;
    unsigned short* wtb   = (unsigned short*)ws;                 // 1 MB
    unsigned short* tp    = (unsigned short*)(ws + 1048576);     // 16 MB
    int*   tidx = (int*)(ws + 17825792);                         // 409600
    float* asum = (float*)(ws + 18235392);                       // 3200
    float* part = (float*)(ws + 18238592);                       // 26.2 MB
    float* qW   = (float*)(ws + 44452992);                       // 8 KB
    float* qb   = (float*)(ws + 44461184);                       // 32 B

    k_trans<<<64, 256, 0, stream>>>(W_tok, wtb);
    k_gemm1<<<M_ / 64, 512, 0, stream>>>(tokens, wtb, b_tok, g_tn, bt_tn, tp);
    k_wavg<<<dim3(32, 8, 5), 256, 0, stream>>>(act, tp, part);
    k_topkqf<<<808, 256, 0, stream>>>(act, tidx, asum, pq, Wq, bq, Wk, bk, qW, qb);
    k_attn<<<B_ * O_, 256, 0, stream>>>(tp, tidx, qW, qb, Wv, bv, Wo, bo,
                                        g_pn, bt_pn, g_on, bt_on, part, asum,
                                        (float*)d_out);
}

// Round 16
// 218.814 us; speedup vs baseline: 1.3479x; 1.1403x over previous
//
#include <hip/hip_runtime.h>
#include <hip/hip_bf16.h>

#define DEVI static __device__ __forceinline__

typedef __attribute__((ext_vector_type(8))) short short8;
typedef __attribute__((ext_vector_type(4))) float f32x4;

#define B_   8
#define O_   100
#define N_   4096
#define TOKD 2048
#define D_   256
#define K_   128
#define H_   8
#define M_   (B_*N_)   // 32768

DEVI unsigned short f2bf(float f) {
    unsigned u = __float_as_uint(f);
    u = (u + 0x7FFFu + ((u >> 16) & 1u)) >> 16;   // RNE
    return (unsigned short)u;
}
DEVI float bf2f(unsigned v) { return __uint_as_float(v << 16); }

DEVI unsigned pkbf(float lo, float hi) {   // packed RNE f32->bf16 pair
    unsigned r;
    asm("v_cvt_pk_bf16_f32 %0, %1, %2" : "=v"(r) : "v"(lo), "v"(hi));
    return r;
}
DEVI void gload16(const void* g, void* l) {   // async global->LDS, 16B/lane
    __builtin_amdgcn_global_load_lds((const __attribute__((address_space(1))) void*)g,
                                     (__attribute__((address_space(3))) void*)l, 16, 0, 0);
}

// ---------- W_tok -> bf16^T, LDS-tiled: coalesced reads AND coalesced 512B writes ----------
__global__ __launch_bounds__(256) void k_trans(const float* __restrict__ W,
                                               unsigned short* __restrict__ wtb) {
    __shared__ unsigned short ldsT[32 * 264];
    const int t = threadIdx.x;
    const int k0 = (blockIdx.x >> 3) * 256;
    const int n0 = (blockIdx.x & 7) * 32;
    const int nn = t & 31, kk8 = t >> 5;
    #pragma unroll
    for (int r = 0; r < 32; ++r) {
        int k = r * 8 + kk8;
        ldsT[nn * 264 + k] = f2bf(W[(size_t)(k0 + k) * D_ + n0 + nn]);
    }
    __syncthreads();
    const int w = t >> 6, l = t & 63;
    #pragma unroll
    for (int rr = 0; rr < 8; ++rr) {
        int n = w * 8 + rr;
        ushort4 v = *(const ushort4*)(&ldsT[n * 264 + l * 4]);
        *(ushort4*)(wtb + (size_t)(n0 + n) * TOKD + k0 + l * 4) = v;
    }
}

// ---------- topk (blocks 0..799) + q-fold (800..807) ----------
__global__ __launch_bounds__(256) void k_topkqf(const float* __restrict__ act,
                                                int* __restrict__ oidx,
                                                float* __restrict__ asum,
                                                const float* __restrict__ pq,
                                                const float* __restrict__ Wq,
                                                const float* __restrict__ bqv,
                                                const float* __restrict__ Wk,
                                                const float* __restrict__ bkv,
                                                float* __restrict__ qW,
                                                float* __restrict__ qb) {
    __shared__ __align__(16) char smem[50304];
    const int t = threadIdx.x, lane = t & 63, wid = t >> 6;

    if (blockIdx.x >= 800) {
        float (*qpart)[32] = (float(*)[32])smem;
        float* qhl = (float*)(smem + 1024);
        const int h = blockIdx.x - 800;
        const int col = h * 32 + (t & 31), sl = t >> 5;
        float s = 0.f;
        #pragma unroll
        for (int e = 0; e < 32; ++e) s += pq[sl * 32 + e] * Wq[(sl * 32 + e) * D_ + col];
        qpart[sl][t & 31] = s;
        __syncthreads();
        if (t < 32) {
            float u = bqv[h * 32 + t];
            #pragma unroll
            for (int s8 = 0; s8 < 8; ++s8) u += qpart[s8][t];
            qhl[t] = u;
        }
        __syncthreads();
        float u = 0.f;
        #pragma unroll
        for (int dd = 0; dd < 32; ++dd) u += qhl[dd] * Wk[t * D_ + h * 32 + dd];
        qW[h * D_ + t] = u;
        if (t == 0) {
            float z = 0.f;
            for (int dd = 0; dd < 32; ++dd) z += qhl[dd] * bkv[h * 32 + dd];
            qb[h] = z;
        }
        return;
    }

    int* hist = (int*)smem;
    unsigned long long* cand = (unsigned long long*)(smem + 16384);
    int* csum = (int*)(smem + 49152);
    int* sb   = (int*)(smem + 50192);
    int* cnts = (int*)(smem + 50200);
    float* redf = (float*)(smem + 50208);
    unsigned long long* redu = (unsigned long long*)(smem + 50224);

    const int blk = blockIdx.x;
    const float* rp = act + (size_t)blk * N_;
    float fv[16]; unsigned vb[16]; int bins[16];
    float fs = 0.f;
    #pragma unroll
    for (int i = 0; i < 16; ++i) {
        float f = rp[t + i * 256];
        fv[i] = f; vb[i] = __float_as_uint(f);
        fs += f;
    }
    #pragma unroll
    for (int i = 0; i < 16; ++i) hist[t + i * 256] = 0;
    if (t == 0) { cnts[0] = 0; cnts[1] = 0; }
    #pragma unroll
    for (int m = 1; m < 64; m <<= 1) fs += __shfl_xor(fs, m);
    if (!lane) redf[wid] = fs;
    __syncthreads();
    if (t == 0) asum[blk] = fmaxf(redf[0] + redf[1] + redf[2] + redf[3], 1e-8f);

    #pragma unroll
    for (int i = 0; i < 16; ++i) {
        float f = fv[i];
        int b = (f >= 1.0f) ? 4095 : ((f > 0.f) ? (int)(f * 4096.f) : 0);
        bins[i] = b;
        atomicAdd(&hist[b], 1);
    }
    __syncthreads();

    int cs = 0;
    #pragma unroll
    for (int i = 0; i < 16; ++i) cs += hist[t * 16 + i];
    int v = cs;
    #pragma unroll
    for (int off = 1; off < 64; off <<= 1) {
        int o = __shfl_down(v, off);
        if (lane + off < 64) v += o;
    }
    if (!lane) csum[256 + wid] = v;
    __syncthreads();
    int stot = 0;
    for (int w2 = wid + 1; w2 < 4; ++w2) stot += csum[256 + w2];
    int suff = v + stot;
    csum[t] = suff;
    __syncthreads();
    int nxtc = (t < 255) ? csum[t + 1] : 0;
    if (suff >= K_ && nxtc < K_) {
        int run = nxtc, bstar = t * 16;
        for (int bi = 15; bi >= 0; --bi) {
            run += hist[t * 16 + bi];
            if (run >= K_) { bstar = t * 16 + bi; break; }
        }
        sb[0] = bstar;
    }
    __syncthreads();
    const int bstar = sb[0];

    #pragma unroll
    for (int i = 0; i < 16; ++i) {
        if (bins[i] > bstar) {
            int p = atomicAdd(&cnts[0], 1);
            oidx[blk * K_ + p] = t + i * 256;
        } else if (bins[i] == bstar) {
            int p = atomicAdd(&cnts[1], 1);
            cand[p] = ((unsigned long long)vb[i] << 16) | (unsigned)(4095 - (t + i * 256));
        }
    }
    __syncthreads();
    const int g = cnts[0], E = cnts[1], m = K_ - g;
    unsigned long long last = ~0ull;
    for (int slot = 0; slot < m; ++slot) {
        unsigned long long best = 0;
        for (int i = t; i < E; i += 256) {
            unsigned long long e = cand[i];
            if (e < last && e > best) best = e;
        }
        #pragma unroll
        for (int mm = 1; mm < 64; mm <<= 1) {
            unsigned long long o = __shfl_xor(best, mm);
            if (o > best) best = o;
        }
        if (!lane) redu[wid] = best;
        __syncthreads();
        best = redu[0];
        if (redu[1] > best) best = redu[1];
        if (redu[2] > best) best = redu[2];
        if (redu[3] > best) best = redu[3];
        if (t == 0) oidx[blk * K_ + g + slot] = 4095 - (int)(best & 0xFFFFull);
        last = best;
        __syncthreads();
    }
}

// ---------- GEMM1 + bias + LN fused (R9 structure: 64x256 tile, BK=64, 80KB LDS, 2 blk/CU) ----------
__global__ __launch_bounds__(512, 2) void k_gemm1(const float* __restrict__ A,
                                                  const unsigned short* __restrict__ Bt,
                                                  const float* __restrict__ btok,
                                                  const float* __restrict__ g,
                                                  const float* __restrict__ bt,
                                                  unsigned short* __restrict__ tp) {
    __shared__ __align__(16) char smem[81920];
    const int t = threadIdx.x;
    const int bm = blockIdx.x;
    const int lane = t & 63, w = t >> 6;
    const int wm = w >> 2, wn = w & 3;       // 2x4 waves, wave tile 32x64
    const int lr = lane >> 4, lc = lane & 15;

    const int arow = t >> 3;
    const int acb = (t & 7) * 16;
    const float* agp = A + (size_t)(bm * 64 + arow) * TOKD + (t & 7) * 8;
    const int aw0 = arow * 128 + (acb ^ ((arow & 7) << 4));
    const unsigned short* bg = Bt + (size_t)(t >> 3) * TOKD
                        + (((((t & 7) << 4)) ^ (((t >> 3) & 7) << 4)) >> 1);
    char* bld = smem + 16384 + (w << 10);

    f32x4 acc[2][4] = {};
    const int NT = TOKD / 64;   // 32
    float4 a0, a1;

    a0 = *(const float4*)(agp); a1 = *(const float4*)(agp + 4);
    #pragma unroll
    for (int c = 0; c < 4; ++c) gload16(bg + (size_t)c * 64 * TOKD, bld + c * 8192);
    {
        uint4 v;
        v.x = pkbf(a0.x, a0.y); v.y = pkbf(a0.z, a0.w);
        v.z = pkbf(a1.x, a1.y); v.w = pkbf(a1.z, a1.w);
        *(uint4*)(smem + aw0) = v;
    }
    a0 = *(const float4*)(agp + 64); a1 = *(const float4*)(agp + 68);
    asm volatile("s_waitcnt vmcnt(2) lgkmcnt(0)" ::: "memory");
    __builtin_amdgcn_s_barrier();

    int cur = 0;
    for (int kt = 0; kt < NT; ++kt) {
        const int nxt = cur ^ 1;
        if (kt + 1 < NT) {
            const unsigned short* bn = bg + (size_t)(kt + 1) * 64;
            char* dst = bld + nxt * 32768;
            #pragma unroll
            for (int c = 0; c < 4; ++c) gload16(bn + (size_t)c * 64 * TOKD, dst + c * 8192);
        }
        const char* Ab = smem + cur * 8192;
        const char* Bb = smem + 16384 + cur * 32768;
        #pragma unroll
        for (int kk = 0; kk < 2; ++kk) {
            short8 afr[2], bfr[4];
            #pragma unroll
            for (int mi = 0; mi < 2; ++mi) {
                int row = wm * 32 + mi * 16 + lc;
                afr[mi] = *(const short8*)(Ab + row * 128 + ((kk * 64 + lr * 16) ^ ((row & 7) << 4)));
            }
            #pragma unroll
            for (int ni = 0; ni < 4; ++ni) {
                int n = wn * 64 + ni * 16 + lc;
                bfr[ni] = *(const short8*)(Bb + n * 128 + ((kk * 64 + lr * 16) ^ ((n & 7) << 4)));
            }
            __builtin_amdgcn_s_setprio(1);
            #pragma unroll
            for (int mi = 0; mi < 2; ++mi)
                #pragma unroll
                for (int ni = 0; ni < 4; ++ni)
                    acc[mi][ni] = __builtin_amdgcn_mfma_f32_16x16x32_bf16(afr[mi], bfr[ni], acc[mi][ni], 0, 0, 0);
            __builtin_amdgcn_s_setprio(0);
        }
        if (kt + 1 < NT) {
            uint4 v;
            v.x = pkbf(a0.x, a0.y); v.y = pkbf(a0.z, a0.w);
            v.z = pkbf(a1.x, a1.y); v.w = pkbf(a1.z, a1.w);
            *(uint4*)(smem + nxt * 8192 + aw0) = v;
            if (kt + 2 < NT) {
                const float* ap = agp + (size_t)(kt + 2) * 64;
                a0 = *(const float4*)(ap); a1 = *(const float4*)(ap + 4);
                asm volatile("s_waitcnt vmcnt(2) lgkmcnt(0)" ::: "memory");
            } else {
                asm volatile("s_waitcnt vmcnt(0) lgkmcnt(0)" ::: "memory");
            }
            __builtin_amdgcn_s_barrier();
            cur = nxt;
        }
    }
    __syncthreads();

    float* ep = (float*)smem;
    const int col0 = lane * 4;
    float4 b4 = *(const float4*)(btok + col0);
    float4 g4 = *(const float4*)(g + col0);
    float4 t4 = *(const float4*)(bt + col0);
    #pragma unroll
    for (int c = 0; c < 2; ++c) {
        if (wm == c) {
            #pragma unroll
            for (int mi = 0; mi < 2; ++mi)
                #pragma unroll
                for (int ni = 0; ni < 4; ++ni)
                    #pragma unroll
                    for (int r = 0; r < 4; ++r)
                        ep[(mi * 16 + lr * 4 + r) * 260 + wn * 64 + ni * 16 + lc] = acc[mi][ni][r];
        }
        __syncthreads();
        #pragma unroll
        for (int rr = 0; rr < 4; ++rr) {
            int row = w * 4 + rr;
            float4 x4 = *(const float4*)(ep + row * 260 + col0);
            float x0 = x4.x + b4.x, x1 = x4.y + b4.y, x2 = x4.z + b4.z, x3 = x4.w + b4.w;
            float s = x0 + x1 + x2 + x3;
            float q = x0*x0 + x1*x1 + x2*x2 + x3*x3;
            #pragma unroll
            for (int m = 1; m < 64; m <<= 1) { s += __shfl_xor(s, m); q += __shfl_xor(q, m); }
            float mean = s * (1.f/256.f);
            float var = q * (1.f/256.f) - mean * mean;
            float rs = rsqrtf(var + 1e-5f);
            ushort4 o;
            o.x = f2bf((x0-mean)*rs*g4.x + t4.x);
            o.y = f2bf((x1-mean)*rs*g4.y + t4.y);
            o.z = f2bf((x2-mean)*rs*g4.z + t4.z);
            o.w = f2bf((x3-mean)*rs*g4.w + t4.w);
            *(ushort4*)(tp + (size_t)(bm * 64 + c * 32 + row) * D_ + col0) = o;
        }
        __syncthreads();
    }
}

// ---------- weighted-average partials (grid z-split x5) ----------
__global__ __launch_bounds__(256) void k_wavg(const float* __restrict__ act,
                                              const unsigned short* __restrict__ tp,
                                              float* __restrict__ partial) {
    const int kc = blockIdx.x;
    const int b = blockIdx.y;
    const int d = threadIdx.x;
    const unsigned short* tpb = tp + ((size_t)b * N_ + kc * 128) * D_ + d;
    const float* actb = act + (size_t)b * O_ * N_ + kc * 128;
    float* pout = partial + ((size_t)(b * 32 + kc) * O_) * D_ + d;
    for (int oci = 0; oci < 2; ++oci) {
        const int oc = blockIdx.z * 2 + oci;
        float acc[10] = {};
        #pragma unroll 2
        for (int q = 0; q < 32; ++q) {
            float t0 = bf2f(tpb[(q * 4 + 0) * D_]);
            float t1 = bf2f(tpb[(q * 4 + 1) * D_]);
            float t2 = bf2f(tpb[(q * 4 + 2) * D_]);
            float t3 = bf2f(tpb[(q * 4 + 3) * D_]);
            #pragma unroll
            for (int oj = 0; oj < 10; ++oj) {
                float4 a4 = *(const float4*)(actb + (size_t)(oc * 10 + oj) * N_ + q * 4);
                acc[oj] += a4.x * t0 + a4.y * t1 + a4.z * t2 + a4.w * t3;
            }
        }
        #pragma unroll
        for (int oj = 0; oj < 10; ++oj)
            pout[(size_t)(oc * 10 + oj) * D_] = acc[oj];
    }
}

// ---------- attention v2: 2-pass tg (32KB), 37KB LDS -> 4 blocks/CU ----------
DEVI int swz64(int j, int chunk) { return j * 512 + ((chunk ^ (j & 31)) << 4); }

__global__ __launch_bounds__(256) void k_attn(
    const unsigned short* __restrict__ tp, const int* __restrict__ oidx,
    const float* __restrict__ qW, const float* __restrict__ qbv,
    const float* __restrict__ Wv, const float* __restrict__ bv,
    const float* __restrict__ Wo, const float* __restrict__ bo,
    const float* __restrict__ g_pn, const float* __restrict__ bt_pn,
    const float* __restrict__ g_on, const float* __restrict__ bt_on,
    const float* __restrict__ partial, const float* __restrict__ asum,
    float* __restrict__ outp)
{
    __shared__ __align__(16) char tg[32768];
    __shared__ float sc[H_ * K_];
    __shared__ float redf[8];
    __shared__ int idxl[K_];
    float* ul = (float*)tg;
    float* pool_lds = (float*)(tg + 8192);

    const int t = threadIdx.x, lane = t & 63, wid = t >> 6;
    const int blk = blockIdx.x;
    const int b = blk / O_;
    const int o = blk - b * O_;

    if (t < K_) idxl[t] = oidx[blk * K_ + t];
    __syncthreads();

    const int jq = t & 63, hp = t >> 6;
    const float* qr0 = qW + (hp * 2) * D_;
    const float* qr1 = qr0 + D_;
    const float sca = 0.1767766952966369f;

    for (int pass = 0; pass < 2; ++pass) {
        #pragma unroll
        for (int it = 0; it < 8; ++it) {
            int c = t + it * 256;
            int j = c >> 5, ch = c & 31;
            uint4 v = *(const uint4*)(tp + ((size_t)(b * N_ + idxl[pass * 64 + j])) * D_ + ch * 8);
            *(uint4*)(tg + swz64(j, ch)) = v;
        }
        __syncthreads();
        float s0 = 0.f, s1 = 0.f;
        #pragma unroll 4
        for (int e8 = 0; e8 < 32; ++e8) {
            uint4 tv = *(const uint4*)(tg + swz64(jq, e8));
            float f0 = bf2f(tv.x & 0xffffu), f1 = bf2f(tv.x >> 16);
            float f2 = bf2f(tv.y & 0xffffu), f3 = bf2f(tv.y >> 16);
            float f4 = bf2f(tv.z & 0xffffu), f5 = bf2f(tv.z >> 16);
            float f6 = bf2f(tv.w & 0xffffu), f7 = bf2f(tv.w >> 16);
            const float* qa = qr0 + e8 * 8;
            const float* qc = qr1 + e8 * 8;
            s0 += f0*qa[0]+f1*qa[1]+f2*qa[2]+f3*qa[3]+f4*qa[4]+f5*qa[5]+f6*qa[6]+f7*qa[7];
            s1 += f0*qc[0]+f1*qc[1]+f2*qc[2]+f3*qc[3]+f4*qc[4]+f5*qc[5]+f6*qc[6]+f7*qc[7];
        }
        sc[(hp * 2)     * K_ + pass * 64 + jq] = (s0 + qbv[hp * 2])     * sca;
        sc[(hp * 2 + 1) * K_ + pass * 64 + jq] = (s1 + qbv[hp * 2 + 1]) * sca;
        __syncthreads();
    }

    #pragma unroll
    for (int hh = 0; hh < 2; ++hh) {
        int h = wid * 2 + hh;
        float v0 = sc[h * K_ + lane], v1 = sc[h * K_ + 64 + lane];
        float mx = fmaxf(v0, v1);
        #pragma unroll
        for (int m = 1; m < 64; m <<= 1) mx = fmaxf(mx, __shfl_xor(mx, m));
        float e0 = __expf(v0 - mx), e1 = __expf(v1 - mx);
        float ss = e0 + e1;
        #pragma unroll
        for (int m = 1; m < 64; m <<= 1) ss += __shfl_xor(ss, m);
        float inv = 1.0f / ss;
        sc[h * K_ + lane] = e0 * inv;
        sc[h * K_ + 64 + lane] = e1 * inv;
    }
    __syncthreads();

    const int hq5 = t >> 5, eg = t & 31;
    float a8[8] = {};
    #pragma unroll 2
    for (int jb = 0; jb < 16; ++jb) {
        f32x4 p4 = *(const f32x4*)(sc + hq5 * K_ + 64 + jb * 4);
        #pragma unroll
        for (int ji = 0; ji < 4; ++ji) {
            int j = jb * 4 + ji;
            uint4 tv = *(const uint4*)(tg + swz64(j, eg));
            float pw = p4[ji];
            a8[0] += pw * bf2f(tv.x & 0xffffu); a8[1] += pw * bf2f(tv.x >> 16);
            a8[2] += pw * bf2f(tv.y & 0xffffu); a8[3] += pw * bf2f(tv.y >> 16);
            a8[4] += pw * bf2f(tv.z & 0xffffu); a8[5] += pw * bf2f(tv.z >> 16);
            a8[6] += pw * bf2f(tv.w & 0xffffu); a8[7] += pw * bf2f(tv.w >> 16);
        }
    }
    __syncthreads();
    #pragma unroll
    for (int it = 0; it < 8; ++it) {
        int c = t + it * 256;
        int j = c >> 5, ch = c & 31;
        uint4 v = *(const uint4*)(tp + ((size_t)(b * N_ + idxl[j])) * D_ + ch * 8);
        *(uint4*)(tg + swz64(j, ch)) = v;
    }
    __syncthreads();
    #pragma unroll 2
    for (int jb = 0; jb < 16; ++jb) {
        f32x4 p4 = *(const f32x4*)(sc + hq5 * K_ + jb * 4);
        #pragma unroll
        for (int ji = 0; ji < 4; ++ji) {
            int j = jb * 4 + ji;
            uint4 tv = *(const uint4*)(tg + swz64(j, eg));
            float pw = p4[ji];
            a8[0] += pw * bf2f(tv.x & 0xffffu); a8[1] += pw * bf2f(tv.x >> 16);
            a8[2] += pw * bf2f(tv.y & 0xffffu); a8[3] += pw * bf2f(tv.y >> 16);
            a8[4] += pw * bf2f(tv.z & 0xffffu); a8[5] += pw * bf2f(tv.z >> 16);
            a8[6] += pw * bf2f(tv.w & 0xffffu); a8[7] += pw * bf2f(tv.w >> 16);
        }
    }
    __syncthreads();
    #pragma unroll
    for (int i = 0; i < 8; ++i) ul[hq5 * D_ + eg * 8 + i] = a8[i];
    __syncthreads();

    {
        int h = t >> 5;
        const float* up = ul + h * D_;
        float p0 = 0.f, p1 = 0.f, p2 = 0.f, p3 = 0.f;
        #pragma unroll 4
        for (int e = 0; e < 64; ++e) {
            p0 += up[e]       * Wv[(size_t)e         * D_ + t];
            p1 += up[e + 64]  * Wv[(size_t)(e + 64)  * D_ + t];
            p2 += up[e + 128] * Wv[(size_t)(e + 128) * D_ + t];
            p3 += up[e + 192] * Wv[(size_t)(e + 192) * D_ + t];
        }
        pool_lds[t] = bv[t] + ((p0 + p1) + (p2 + p3));
    }
    __syncthreads();
    float po;
    {
        float p0 = 0.f, p1 = 0.f, p2 = 0.f, p3 = 0.f;
        #pragma unroll 4
        for (int e = 0; e < 64; ++e) {
            p0 += pool_lds[e]       * Wo[(size_t)e         * D_ + t];
            p1 += pool_lds[e + 64]  * Wo[(size_t)(e + 64)  * D_ + t];
            p2 += pool_lds[e + 128] * Wo[(size_t)(e + 128) * D_ + t];
            p3 += pool_lds[e + 192] * Wo[(size_t)(e + 192) * D_ + t];
        }
        po = bo[t] + ((p0 + p1) + (p2 + p3));
    }

    float lsm = po, lqm = po * po;
    #pragma unroll
    for (int m = 1; m < 64; m <<= 1) { lsm += __shfl_xor(lsm, m); lqm += __shfl_xor(lqm, m); }
    if (!lane) { redf[wid] = lsm; redf[4 + wid] = lqm; }
    __syncthreads();
    lsm = redf[0] + redf[1] + redf[2] + redf[3];
    lqm = redf[4] + redf[5] + redf[6] + redf[7];
    float mean = lsm * (1.f/256.f);
    float var = lqm * (1.f/256.f) - mean * mean;
    float rs = rsqrtf(var + 1e-5f);
    float pl = (po - mean) * rs * g_pn[t] + bt_pn[t];
    __syncthreads();

    float wa = 0.f;
    const float* pp = partial + ((size_t)(b * 32) * O_ + o) * D_ + t;
    #pragma unroll 8
    for (int kc = 0; kc < 32; ++kc) wa += pp[(size_t)kc * O_ * D_];
    float x = wa / asum[blk] + pl;
    float s2 = x, q2 = x * x;
    #pragma unroll
    for (int m = 1; m < 64; m <<= 1) { s2 += __shfl_xor(s2, m); q2 += __shfl_xor(q2, m); }
    if (!lane) { redf[wid] = s2; redf[4 + wid] = q2; }
    __syncthreads();
    s2 = redf[0] + redf[1] + redf[2] + redf[3];
    q2 = redf[4] + redf[5] + redf[6] + redf[7];
    float mean2 = s2 * (1.f/256.f);
    float var2 = q2 * (1.f/256.f) - mean2 * mean2;
    float rs2 = rsqrtf(var2 + 1e-5f);
    outp[(size_t)blk * D_ + t] = (x - mean2) * rs2 * g_on[t] + bt_on[t];
}

extern "C" void kernel_launch(void* const* d_in, const int* in_sizes, int n_in,
                              void* d_out, int out_size, void* d_ws, size_t ws_size,
                              hipStream_t stream) {
    const float* act    = (const float*)d_in[0];
    const float* tokens = (const float*)d_in[1];
    const float* W_tok  = (const float*)d_in[2];
    const float* b_tok  = (const float*)d_in[3];
    const float* g_tn   = (const float*)d_in[4];
    const float* bt_tn  = (const float*)d_in[5];
    const float* pq     = (const float*)d_in[6];
    const float* Wq     = (const float*)d_in[7];
    const float* bq     = (const float*)d_in[8];
    const float* Wk     = (const float*)d_in[9];
    const float* bk     = (const float*)d_in[10];
    const float* Wv     = (const float*)d_in[11];
    const float* bv     = (const float*)d_in[12];
    const float* Wo     = (const float*)d_in[13];
    const float* bo     = (const float*)d_in[14];
    const float* g_pn   = (const float*)d_in[15];
    const float* bt_pn  = (const float*)d_in[16];
    const float* g_on   = (const float*)d_in[17];
    const float* bt_on  = (const float*)d_in[18];

    char* ws = (char*)d_ws;
    unsigned short* wtb   = (unsigned short*)ws;                 // 1 MB
    unsigned short* tp    = (unsigned short*)(ws + 1048576);     // 16 MB
    int*   tidx = (int*)(ws + 17825792);                         // 409600
    float* asum = (float*)(ws + 18235392);                       // 3200
    float* part = (float*)(ws + 18238592);                       // 26.2 MB
    float* qW   = (float*)(ws + 44452992);                       // 8 KB
    float* qb   = (float*)(ws + 44461184);                       // 32 B

    k_trans<<<64, 256, 0, stream>>>(W_tok, wtb);
    k_gemm1<<<M_ / 64, 512, 0, stream>>>(tokens, wtb, b_tok, g_tn, bt_tn, tp);
    k_wavg<<<dim3(32, 8, 5), 256, 0, stream>>>(act, tp, part);
    k_topkqf<<<808, 256, 0, stream>>>(act, tidx, asum, pq, Wq, bq, Wk, bk, qW, qb);
    k_attn<<<B_ * O_, 256, 0, stream>>>(tp, tidx, qW, qb, Wv, bv, Wo, bo,
                                        g_pn, bt_pn, g_on, bt_on, part, asum,
                                        (float*)d_out);
}

// Round 17
// 212.125 us; speedup vs baseline: 1.3904x; 1.0315x over previous
//
#include <hip/hip_runtime.h>
#include <hip/hip_bf16.h>

#define DEVI static __device__ __forceinline__

typedef __attribute__((ext_vector_type(8))) short short8;
typedef __attribute__((ext_vector_type(4))) float f32x4;

#define B_   8
#define O_   100
#define N_   4096
#define TOKD 2048
#define D_   256
#define K_   128
#define H_   8
#define M_   (B_*N_)   // 32768

DEVI unsigned short f2bf(float f) {
    unsigned u = __float_as_uint(f);
    u = (u + 0x7FFFu + ((u >> 16) & 1u)) >> 16;   // RNE
    return (unsigned short)u;
}
DEVI float bf2f(unsigned v) { return __uint_as_float(v << 16); }

DEVI unsigned pkbf(float lo, float hi) {   // packed RNE f32->bf16 pair
    unsigned r;
    asm("v_cvt_pk_bf16_f32 %0, %1, %2" : "=v"(r) : "v"(lo), "v"(hi));
    return r;
}
DEVI void gload16(const void* g, void* l) {   // async global->LDS, 16B/lane
    __builtin_amdgcn_global_load_lds((const __attribute__((address_space(1))) void*)g,
                                     (__attribute__((address_space(3))) void*)l, 16, 0, 0);
}

// ---------- merged pre-gemm: topk (0..799) + q-fold (800..807) + W_tok transpose (808..871) ----------
__global__ __launch_bounds__(256) void k_pre(const float* __restrict__ act,
                                             int* __restrict__ oidx,
                                             float* __restrict__ asum,
                                             const float* __restrict__ pq,
                                             const float* __restrict__ Wq,
                                             const float* __restrict__ bqv,
                                             const float* __restrict__ Wk,
                                             const float* __restrict__ bkv,
                                             float* __restrict__ qW,
                                             float* __restrict__ qb,
                                             const float* __restrict__ W,
                                             unsigned short* __restrict__ wtb) {
    __shared__ __align__(16) char smem[50304];
    const int t = threadIdx.x, lane = t & 63, wid = t >> 6;

    if (blockIdx.x >= 808) {
        // ---- W_tok -> bf16^T tile: coalesced reads AND coalesced 512B writes
        unsigned short* ldsT = (unsigned short*)smem;   // 32 x 264
        const int bx = blockIdx.x - 808;
        const int k0 = (bx >> 3) * 256;
        const int n0 = (bx & 7) * 32;
        const int nn = t & 31, kk8 = t >> 5;
        #pragma unroll
        for (int r = 0; r < 32; ++r) {
            int k = r * 8 + kk8;
            ldsT[nn * 264 + k] = f2bf(W[(size_t)(k0 + k) * D_ + n0 + nn]);
        }
        __syncthreads();
        const int w = t >> 6, l = t & 63;
        #pragma unroll
        for (int rr = 0; rr < 8; ++rr) {
            int n = w * 8 + rr;
            ushort4 v = *(const ushort4*)(&ldsT[n * 264 + l * 4]);
            *(ushort4*)(wtb + (size_t)(n0 + n) * TOKD + k0 + l * 4) = v;
        }
        return;
    }

    if (blockIdx.x >= 800) {
        // ---- q-fold: qW[h][e] = qh[h]·Wk[e][h*32..], qb[h]
        float (*qpart)[32] = (float(*)[32])smem;
        float* qhl = (float*)(smem + 1024);
        const int h = blockIdx.x - 800;
        const int col = h * 32 + (t & 31), sl = t >> 5;
        float s = 0.f;
        #pragma unroll
        for (int e = 0; e < 32; ++e) s += pq[sl * 32 + e] * Wq[(sl * 32 + e) * D_ + col];
        qpart[sl][t & 31] = s;
        __syncthreads();
        if (t < 32) {
            float u = bqv[h * 32 + t];
            #pragma unroll
            for (int s8 = 0; s8 < 8; ++s8) u += qpart[s8][t];
            qhl[t] = u;
        }
        __syncthreads();
        float u = 0.f;
        #pragma unroll
        for (int dd = 0; dd < 32; ++dd) u += qhl[dd] * Wk[t * D_ + h * 32 + dd];
        qW[h * D_ + t] = u;
        if (t == 0) {
            float z = 0.f;
            for (int dd = 0; dd < 32; ++dd) z += qhl[dd] * bkv[h * 32 + dd];
            qb[h] = z;
        }
        return;
    }

    // ---- top-128 via value histogram (act uniform [0,1); exact jax tie-break at boundary)
    int* hist = (int*)smem;
    unsigned long long* cand = (unsigned long long*)(smem + 16384);
    int* csum = (int*)(smem + 49152);
    int* sb   = (int*)(smem + 50192);
    int* cnts = (int*)(smem + 50200);
    float* redf = (float*)(smem + 50208);
    unsigned long long* redu = (unsigned long long*)(smem + 50224);

    const int blk = blockIdx.x;
    const float* rp = act + (size_t)blk * N_;
    float fv[16]; unsigned vb[16]; int bins[16];
    float fs = 0.f;
    #pragma unroll
    for (int i = 0; i < 16; ++i) {
        float f = rp[t + i * 256];
        fv[i] = f; vb[i] = __float_as_uint(f);
        fs += f;
    }
    #pragma unroll
    for (int i = 0; i < 16; ++i) hist[t + i * 256] = 0;
    if (t == 0) { cnts[0] = 0; cnts[1] = 0; }
    #pragma unroll
    for (int m = 1; m < 64; m <<= 1) fs += __shfl_xor(fs, m);
    if (!lane) redf[wid] = fs;
    __syncthreads();
    if (t == 0) asum[blk] = fmaxf(redf[0] + redf[1] + redf[2] + redf[3], 1e-8f);

    #pragma unroll
    for (int i = 0; i < 16; ++i) {
        float f = fv[i];
        int b = (f >= 1.0f) ? 4095 : ((f > 0.f) ? (int)(f * 4096.f) : 0);
        bins[i] = b;
        atomicAdd(&hist[b], 1);
    }
    __syncthreads();

    int cs = 0;
    #pragma unroll
    for (int i = 0; i < 16; ++i) cs += hist[t * 16 + i];
    int v = cs;
    #pragma unroll
    for (int off = 1; off < 64; off <<= 1) {
        int o = __shfl_down(v, off);
        if (lane + off < 64) v += o;
    }
    if (!lane) csum[256 + wid] = v;
    __syncthreads();
    int stot = 0;
    for (int w2 = wid + 1; w2 < 4; ++w2) stot += csum[256 + w2];
    int suff = v + stot;
    csum[t] = suff;
    __syncthreads();
    int nxtc = (t < 255) ? csum[t + 1] : 0;
    if (suff >= K_ && nxtc < K_) {
        int run = nxtc, bstar = t * 16;
        for (int bi = 15; bi >= 0; --bi) {
            run += hist[t * 16 + bi];
            if (run >= K_) { bstar = t * 16 + bi; break; }
        }
        sb[0] = bstar;
    }
    __syncthreads();
    const int bstar = sb[0];

    #pragma unroll
    for (int i = 0; i < 16; ++i) {
        if (bins[i] > bstar) {
            int p = atomicAdd(&cnts[0], 1);
            oidx[blk * K_ + p] = t + i * 256;
        } else if (bins[i] == bstar) {
            int p = atomicAdd(&cnts[1], 1);
            cand[p] = ((unsigned long long)vb[i] << 16) | (unsigned)(4095 - (t + i * 256));
        }
    }
    __syncthreads();
    const int g = cnts[0], E = cnts[1], m = K_ - g;
    unsigned long long last = ~0ull;
    for (int slot = 0; slot < m; ++slot) {
        unsigned long long best = 0;
        for (int i = t; i < E; i += 256) {
            unsigned long long e = cand[i];
            if (e < last && e > best) best = e;
        }
        #pragma unroll
        for (int mm = 1; mm < 64; mm <<= 1) {
            unsigned long long o = __shfl_xor(best, mm);
            if (o > best) best = o;
        }
        if (!lane) redu[wid] = best;
        __syncthreads();
        best = redu[0];
        if (redu[1] > best) best = redu[1];
        if (redu[2] > best) best = redu[2];
        if (redu[3] > best) best = redu[3];
        if (t == 0) oidx[blk * K_ + g + slot] = 4095 - (int)(best & 0xFFFFull);
        last = best;
        __syncthreads();
    }
}

// ---------- GEMM1 + bias + LN fused (R9 structure: 64x256 tile, BK=64, 80KB LDS, 2 blk/CU) ----------
__global__ __launch_bounds__(512, 2) void k_gemm1(const float* __restrict__ A,
                                                  const unsigned short* __restrict__ Bt,
                                                  const float* __restrict__ btok,
                                                  const float* __restrict__ g,
                                                  const float* __restrict__ bt,
                                                  unsigned short* __restrict__ tp) {
    __shared__ __align__(16) char smem[81920];
    const int t = threadIdx.x;
    const int bm = blockIdx.x;
    const int lane = t & 63, w = t >> 6;
    const int wm = w >> 2, wn = w & 3;       // 2x4 waves, wave tile 32x64
    const int lr = lane >> 4, lc = lane & 15;

    const int arow = t >> 3;
    const int acb = (t & 7) * 16;
    const float* agp = A + (size_t)(bm * 64 + arow) * TOKD + (t & 7) * 8;
    const int aw0 = arow * 128 + (acb ^ ((arow & 7) << 4));
    const unsigned short* bg = Bt + (size_t)(t >> 3) * TOKD
                        + (((((t & 7) << 4)) ^ (((t >> 3) & 7) << 4)) >> 1);
    char* bld = smem + 16384 + (w << 10);

    f32x4 acc[2][4] = {};
    const int NT = TOKD / 64;   // 32
    float4 a0, a1;

    a0 = *(const float4*)(agp); a1 = *(const float4*)(agp + 4);
    #pragma unroll
    for (int c = 0; c < 4; ++c) gload16(bg + (size_t)c * 64 * TOKD, bld + c * 8192);
    {
        uint4 v;
        v.x = pkbf(a0.x, a0.y); v.y = pkbf(a0.z, a0.w);
        v.z = pkbf(a1.x, a1.y); v.w = pkbf(a1.z, a1.w);
        *(uint4*)(smem + aw0) = v;
    }
    a0 = *(const float4*)(agp + 64); a1 = *(const float4*)(agp + 68);
    asm volatile("s_waitcnt vmcnt(2) lgkmcnt(0)" ::: "memory");
    __builtin_amdgcn_s_barrier();

    int cur = 0;
    for (int kt = 0; kt < NT; ++kt) {
        const int nxt = cur ^ 1;
        if (kt + 1 < NT) {
            const unsigned short* bn = bg + (size_t)(kt + 1) * 64;
            char* dst = bld + nxt * 32768;
            #pragma unroll
            for (int c = 0; c < 4; ++c) gload16(bn + (size_t)c * 64 * TOKD, dst + c * 8192);
        }
        const char* Ab = smem + cur * 8192;
        const char* Bb = smem + 16384 + cur * 32768;
        #pragma unroll
        for (int kk = 0; kk < 2; ++kk) {
            short8 afr[2], bfr[4];
            #pragma unroll
            for (int mi = 0; mi < 2; ++mi) {
                int row = wm * 32 + mi * 16 + lc;
                afr[mi] = *(const short8*)(Ab + row * 128 + ((kk * 64 + lr * 16) ^ ((row & 7) << 4)));
            }
            #pragma unroll
            for (int ni = 0; ni < 4; ++ni) {
                int n = wn * 64 + ni * 16 + lc;
                bfr[ni] = *(const short8*)(Bb + n * 128 + ((kk * 64 + lr * 16) ^ ((n & 7) << 4)));
            }
            __builtin_amdgcn_s_setprio(1);
            #pragma unroll
            for (int mi = 0; mi < 2; ++mi)
                #pragma unroll
                for (int ni = 0; ni < 4; ++ni)
                    acc[mi][ni] = __builtin_amdgcn_mfma_f32_16x16x32_bf16(afr[mi], bfr[ni], acc[mi][ni], 0, 0, 0);
            __builtin_amdgcn_s_setprio(0);
        }
        if (kt + 1 < NT) {
            uint4 v;
            v.x = pkbf(a0.x, a0.y); v.y = pkbf(a0.z, a0.w);
            v.z = pkbf(a1.x, a1.y); v.w = pkbf(a1.z, a1.w);
            *(uint4*)(smem + nxt * 8192 + aw0) = v;
            if (kt + 2 < NT) {
                const float* ap = agp + (size_t)(kt + 2) * 64;
                a0 = *(const float4*)(ap); a1 = *(const float4*)(ap + 4);
                asm volatile("s_waitcnt vmcnt(2) lgkmcnt(0)" ::: "memory");
            } else {
                asm volatile("s_waitcnt vmcnt(0) lgkmcnt(0)" ::: "memory");
            }
            __builtin_amdgcn_s_barrier();
            cur = nxt;
        }
    }
    __syncthreads();

    float* ep = (float*)smem;
    const int col0 = lane * 4;
    float4 b4 = *(const float4*)(btok + col0);
    float4 g4 = *(const float4*)(g + col0);
    float4 t4 = *(const float4*)(bt + col0);
    #pragma unroll
    for (int c = 0; c < 2; ++c) {
        if (wm == c) {
            #pragma unroll
            for (int mi = 0; mi < 2; ++mi)
                #pragma unroll
                for (int ni = 0; ni < 4; ++ni)
                    #pragma unroll
                    for (int r = 0; r < 4; ++r)
                        ep[(mi * 16 + lr * 4 + r) * 260 + wn * 64 + ni * 16 + lc] = acc[mi][ni][r];
        }
        __syncthreads();
        #pragma unroll
        for (int rr = 0; rr < 4; ++rr) {
            int row = w * 4 + rr;
            float4 x4 = *(const float4*)(ep + row * 260 + col0);
            float x0 = x4.x + b4.x, x1 = x4.y + b4.y, x2 = x4.z + b4.z, x3 = x4.w + b4.w;
            float s = x0 + x1 + x2 + x3;
            float q = x0*x0 + x1*x1 + x2*x2 + x3*x3;
            #pragma unroll
            for (int m = 1; m < 64; m <<= 1) { s += __shfl_xor(s, m); q += __shfl_xor(q, m); }
            float mean = s * (1.f/256.f);
            float var = q * (1.f/256.f) - mean * mean;
            float rs = rsqrtf(var + 1e-5f);
            ushort4 o;
            o.x = f2bf((x0-mean)*rs*g4.x + t4.x);
            o.y = f2bf((x1-mean)*rs*g4.y + t4.y);
            o.z = f2bf((x2-mean)*rs*g4.z + t4.z);
            o.w = f2bf((x3-mean)*rs*g4.w + t4.w);
            *(ushort4*)(tp + (size_t)(bm * 64 + c * 32 + row) * D_ + col0) = o;
        }
        __syncthreads();
    }
}

// ---------- weighted-average partials (grid z-split x5) ----------
__global__ __launch_bounds__(256) void k_wavg(const float* __restrict__ act,
                                              const unsigned short* __restrict__ tp,
                                              float* __restrict__ partial) {
    const int kc = blockIdx.x;
    const int b = blockIdx.y;
    const int d = threadIdx.x;
    const unsigned short* tpb = tp + ((size_t)b * N_ + kc * 128) * D_ + d;
    const float* actb = act + (size_t)b * O_ * N_ + kc * 128;
    float* pout = partial + ((size_t)(b * 32 + kc) * O_) * D_ + d;
    for (int oci = 0; oci < 2; ++oci) {
        const int oc = blockIdx.z * 2 + oci;
        float acc[10] = {};
        #pragma unroll 2
        for (int q = 0; q < 32; ++q) {
            float t0 = bf2f(tpb[(q * 4 + 0) * D_]);
            float t1 = bf2f(tpb[(q * 4 + 1) * D_]);
            float t2 = bf2f(tpb[(q * 4 + 2) * D_]);
            float t3 = bf2f(tpb[(q * 4 + 3) * D_]);
            #pragma unroll
            for (int oj = 0; oj < 10; ++oj) {
                float4 a4 = *(const float4*)(actb + (size_t)(oc * 10 + oj) * N_ + q * 4);
                acc[oj] += a4.x * t0 + a4.y * t1 + a4.z * t2 + a4.w * t3;
            }
        }
        #pragma unroll
        for (int oj = 0; oj < 10; ++oj)
            pout[(size_t)(oc * 10 + oj) * D_] = acc[oj];
    }
}

// ---------- attention v2: 2-pass tg (32KB), 37KB LDS -> 4 blocks/CU ----------
DEVI int swz64(int j, int chunk) { return j * 512 + ((chunk ^ (j & 31)) << 4); }

__global__ __launch_bounds__(256) void k_attn(
    const unsigned short* __restrict__ tp, const int* __restrict__ oidx,
    const float* __restrict__ qW, const float* __restrict__ qbv,
    const float* __restrict__ Wv, const float* __restrict__ bv,
    const float* __restrict__ Wo, const float* __restrict__ bo,
    const float* __restrict__ g_pn, const float* __restrict__ bt_pn,
    const float* __restrict__ g_on, const float* __restrict__ bt_on,
    const float* __restrict__ partial, const float* __restrict__ asum,
    float* __restrict__ outp)
{
    __shared__ __align__(16) char tg[32768];
    __shared__ float sc[H_ * K_];
    __shared__ float redf[8];
    __shared__ int idxl[K_];
    float* ul = (float*)tg;
    float* pool_lds = (float*)(tg + 8192);

    const int t = threadIdx.x, lane = t & 63, wid = t >> 6;
    const int blk = blockIdx.x;
    const int b = blk / O_;
    const int o = blk - b * O_;

    if (t < K_) idxl[t] = oidx[blk * K_ + t];
    __syncthreads();

    const int jq = t & 63, hp = t >> 6;
    const float* qr0 = qW + (hp * 2) * D_;
    const float* qr1 = qr0 + D_;
    const float sca = 0.1767766952966369f;

    for (int pass = 0; pass < 2; ++pass) {
        #pragma unroll
        for (int it = 0; it < 8; ++it) {
            int c = t + it * 256;
            int j = c >> 5, ch = c & 31;
            uint4 v = *(const uint4*)(tp + ((size_t)(b * N_ + idxl[pass * 64 + j])) * D_ + ch * 8);
            *(uint4*)(tg + swz64(j, ch)) = v;
        }
        __syncthreads();
        float s0 = 0.f, s1 = 0.f;
        #pragma unroll 4
        for (int e8 = 0; e8 < 32; ++e8) {
            uint4 tv = *(const uint4*)(tg + swz64(jq, e8));
            float f0 = bf2f(tv.x & 0xffffu), f1 = bf2f(tv.x >> 16);
            float f2 = bf2f(tv.y & 0xffffu), f3 = bf2f(tv.y >> 16);
            float f4 = bf2f(tv.z & 0xffffu), f5 = bf2f(tv.z >> 16);
            float f6 = bf2f(tv.w & 0xffffu), f7 = bf2f(tv.w >> 16);
            const float* qa = qr0 + e8 * 8;
            const float* qc = qr1 + e8 * 8;
            s0 += f0*qa[0]+f1*qa[1]+f2*qa[2]+f3*qa[3]+f4*qa[4]+f5*qa[5]+f6*qa[6]+f7*qa[7];
            s1 += f0*qc[0]+f1*qc[1]+f2*qc[2]+f3*qc[3]+f4*qc[4]+f5*qc[5]+f6*qc[6]+f7*qc[7];
        }
        sc[(hp * 2)     * K_ + pass * 64 + jq] = (s0 + qbv[hp * 2])     * sca;
        sc[(hp * 2 + 1) * K_ + pass * 64 + jq] = (s1 + qbv[hp * 2 + 1]) * sca;
        __syncthreads();
    }

    #pragma unroll
    for (int hh = 0; hh < 2; ++hh) {
        int h = wid * 2 + hh;
        float v0 = sc[h * K_ + lane], v1 = sc[h * K_ + 64 + lane];
        float mx = fmaxf(v0, v1);
        #pragma unroll
        for (int m = 1; m < 64; m <<= 1) mx = fmaxf(mx, __shfl_xor(mx, m));
        float e0 = __expf(v0 - mx), e1 = __expf(v1 - mx);
        float ss = e0 + e1;
        #pragma unroll
        for (int m = 1; m < 64; m <<= 1) ss += __shfl_xor(ss, m);
        float inv = 1.0f / ss;
        sc[h * K_ + lane] = e0 * inv;
        sc[h * K_ + 64 + lane] = e1 * inv;
    }
    __syncthreads();

    const int hq5 = t >> 5, eg = t & 31;
    float a8[8] = {};
    #pragma unroll 2
    for (int jb = 0; jb < 16; ++jb) {
        f32x4 p4 = *(const f32x4*)(sc + hq5 * K_ + 64 + jb * 4);
        #pragma unroll
        for (int ji = 0; ji < 4; ++ji) {
            int j = jb * 4 + ji;
            uint4 tv = *(const uint4*)(tg + swz64(j, eg));
            float pw = p4[ji];
            a8[0] += pw * bf2f(tv.x & 0xffffu); a8[1] += pw * bf2f(tv.x >> 16);
            a8[2] += pw * bf2f(tv.y & 0xffffu); a8[3] += pw * bf2f(tv.y >> 16);
            a8[4] += pw * bf2f(tv.z & 0xffffu); a8[5] += pw * bf2f(tv.z >> 16);
            a8[6] += pw * bf2f(tv.w & 0xffffu); a8[7] += pw * bf2f(tv.w >> 16);
        }
    }
    __syncthreads();
    #pragma unroll
    for (int it = 0; it < 8; ++it) {
        int c = t + it * 256;
        int j = c >> 5, ch = c & 31;
        uint4 v = *(const uint4*)(tp + ((size_t)(b * N_ + idxl[j])) * D_ + ch * 8);
        *(uint4*)(tg + swz64(j, ch)) = v;
    }
    __syncthreads();
    #pragma unroll 2
    for (int jb = 0; jb < 16; ++jb) {
        f32x4 p4 = *(const f32x4*)(sc + hq5 * K_ + jb * 4);
        #pragma unroll
        for (int ji = 0; ji < 4; ++ji) {
            int j = jb * 4 + ji;
            uint4 tv = *(const uint4*)(tg + swz64(j, eg));
            float pw = p4[ji];
            a8[0] += pw * bf2f(tv.x & 0xffffu); a8[1] += pw * bf2f(tv.x >> 16);
            a8[2] += pw * bf2f(tv.y & 0xffffu); a8[3] += pw * bf2f(tv.y >> 16);
            a8[4] += pw * bf2f(tv.z & 0xffffu); a8[5] += pw * bf2f(tv.z >> 16);
            a8[6] += pw * bf2f(tv.w & 0xffffu); a8[7] += pw * bf2f(tv.w >> 16);
        }
    }
    __syncthreads();
    #pragma unroll
    for (int i = 0; i < 8; ++i) ul[hq5 * D_ + eg * 8 + i] = a8[i];
    __syncthreads();

    {
        int h = t >> 5;
        const float* up = ul + h * D_;
        float p0 = 0.f, p1 = 0.f, p2 = 0.f, p3 = 0.f;
        #pragma unroll 4
        for (int e = 0; e < 64; ++e) {
            p0 += up[e]       * Wv[(size_t)e         * D_ + t];
            p1 += up[e + 64]  * Wv[(size_t)(e + 64)  * D_ + t];
            p2 += up[e + 128] * Wv[(size_t)(e + 128) * D_ + t];
            p3 += up[e + 192] * Wv[(size_t)(e + 192) * D_ + t];
        }
        pool_lds[t] = bv[t] + ((p0 + p1) + (p2 + p3));
    }
    __syncthreads();
    float po;
    {
        float p0 = 0.f, p1 = 0.f, p2 = 0.f, p3 = 0.f;
        #pragma unroll 4
        for (int e = 0; e < 64; ++e) {
            p0 += pool_lds[e]       * Wo[(size_t)e         * D_ + t];
            p1 += pool_lds[e + 64]  * Wo[(size_t)(e + 64)  * D_ + t];
            p2 += pool_lds[e + 128] * Wo[(size_t)(e + 128) * D_ + t];
            p3 += pool_lds[e + 192] * Wo[(size_t)(e + 192) * D_ + t];
        }
        po = bo[t] + ((p0 + p1) + (p2 + p3));
    }

    float lsm = po, lqm = po * po;
    #pragma unroll
    for (int m = 1; m < 64; m <<= 1) { lsm += __shfl_xor(lsm, m); lqm += __shfl_xor(lqm, m); }
    if (!lane) { redf[wid] = lsm; redf[4 + wid] = lqm; }
    __syncthreads();
    lsm = redf[0] + redf[1] + redf[2] + redf[3];
    lqm = redf[4] + redf[5] + redf[6] + redf[7];
    float mean = lsm * (1.f/256.f);
    float var = lqm * (1.f/256.f) - mean * mean;
    float rs = rsqrtf(var + 1e-5f);
    float pl = (po - mean) * rs * g_pn[t] + bt_pn[t];
    __syncthreads();

    float wa = 0.f;
    const float* pp = partial + ((size_t)(b * 32) * O_ + o) * D_ + t;
    #pragma unroll 8
    for (int kc = 0; kc < 32; ++kc) wa += pp[(size_t)kc * O_ * D_];
    float x = wa / asum[blk] + pl;
    float s2 = x, q2 = x * x;
    #pragma unroll
    for (int m = 1; m < 64; m <<= 1) { s2 += __shfl_xor(s2, m); q2 += __shfl_xor(q2, m); }
    if (!lane) { redf[wid] = s2; redf[4 + wid] = q2; }
    __syncthreads();
    s2 = redf[0] + redf[1] + redf[2] + redf[3];
    q2 = redf[4] + redf[5] + redf[6] + redf[7];
    float mean2 = s2 * (1.f/256.f);
    float var2 = q2 * (1.f/256.f) - mean2 * mean2;
    float rs2 = rsqrtf(var2 + 1e-5f);
    outp[(size_t)blk * D_ + t] = (x - mean2) * rs2 * g_on[t] + bt_on[t];
}

extern "C" void kernel_launch(void* const* d_in, const int* in_sizes, int n_in,
                              void* d_out, int out_size, void* d_ws, size_t ws_size,
                              hipStream_t stream) {
    const float* act    = (const float*)d_in[0];
    const float* tokens = (const float*)d_in[1];
    const float* W_tok  = (const float*)d_in[2];
    const float* b_tok  = (const float*)d_in[3];
    const float* g_tn   = (const float*)d_in[4];
    const float* bt_tn  = (const float*)d_in[5];
    const float* pq     = (const float*)d_in[6];
    const float* Wq     = (const float*)d_in[7];
    const float* bq     = (const float*)d_in[8];
    const float* Wk     = (const float*)d_in[9];
    const float* bk     = (const float*)d_in[10];
    const float* Wv     = (const float*)d_in[11];
    const float* bv     = (const float*)d_in[12];
    const float* Wo     = (const float*)d_in[13];
    const float* bo     = (const float*)d_in[14];
    const float* g_pn   = (const float*)d_in[15];
    const float* bt_pn  = (const float*)d_in[16];
    const float* g_on   = (const float*)d_in[17];
    const float* bt_on  = (const float*)d_in[18];

    char* ws = (char*)d_ws;
    unsigned short* wtb   = (unsigned short*)ws;                 // 1 MB
    unsigned short* tp    = (unsigned short*)(ws + 1048576);     // 16 MB
    int*   tidx = (int*)(ws + 17825792);                         // 409600
    float* asum = (float*)(ws + 18235392);                       // 3200
    float* part = (float*)(ws + 18238592);                       // 26.2 MB
    float* qW   = (float*)(ws + 44452992);                       // 8 KB
    float* qb   = (float*)(ws + 44461184);                       // 32 B

    k_pre<<<872, 256, 0, stream>>>(act, tidx, asum, pq, Wq, bq, Wk, bk, qW, qb,
                                   W_tok, wtb);
    k_gemm1<<<M_ / 64, 512, 0, stream>>>(tokens, wtb, b_tok, g_tn, bt_tn, tp);
    k_wavg<<<dim3(32, 8, 5), 256, 0, stream>>>(act, tp, part);
    k_attn<<<B_ * O_, 256, 0, stream>>>(tp, tidx, qW, qb, Wv, bv, Wo, bo,
                                        g_pn, bt_pn, g_on, bt_on, part, asum,
                                        (float*)d_out);
}